// Round 2
// baseline (155424.768 us; speedup 1.0000x reference)
//
#include <hip/hip_runtime.h>
#include <stdint.h>

typedef long long i64;

#define SV 11
#define SE 17
#define ARITY 10
#define NHEDGE 32768
#define NNODE 65536
#define NTOTAL 100000

__device__ __forceinline__ float wredsum(float s) {
#pragma unroll
  for (int o = 32; o > 0; o >>= 1) s += __shfl_xor(s, o, 64);
  return s;
}

// ---------------- GEMM: C[M,N] = act(A[M,K] @ W[N,K]^T + bias) ----------------
// MODE: 0 = none, 1 = +bias, 2 = +bias+relu
template <int K, int MODE>
__global__ __launch_bounds__(256) void gemm_k(const float* __restrict__ A,
                                              const float* __restrict__ W,
                                              const float* __restrict__ bias,
                                              float* __restrict__ C, int M, int N) {
  __shared__ float As[32][128];  // [k][m]
  __shared__ float Ws[32][128];  // [k][n]
  const int tid = threadIdx.x;
  const int m0 = blockIdx.y << 7, n0 = blockIdx.x << 7;
  const int tx = tid & 15, ty = tid >> 4;

  float acc[8][8];
#pragma unroll
  for (int i = 0; i < 8; i++)
#pragma unroll
    for (int j = 0; j < 8; j++) acc[i][j] = 0.f;

  const int lr = tid & 127;        // tile row this thread stages
  const int lh = (tid >> 7) << 4;  // k-offset 0 or 16
  const float* Ag = A + (i64)(m0 + lr) * K + lh;
  const float* Wg = W + (i64)(n0 + lr) * K + lh;

  for (int k0 = 0; k0 < K; k0 += 32) {
    float4 av0 = *(const float4*)(Ag + k0);
    float4 av1 = *(const float4*)(Ag + k0 + 4);
    float4 av2 = *(const float4*)(Ag + k0 + 8);
    float4 av3 = *(const float4*)(Ag + k0 + 12);
    float4 wv0 = *(const float4*)(Wg + k0);
    float4 wv1 = *(const float4*)(Wg + k0 + 4);
    float4 wv2 = *(const float4*)(Wg + k0 + 8);
    float4 wv3 = *(const float4*)(Wg + k0 + 12);
    __syncthreads();  // previous iter's LDS reads done
    As[lh + 0][lr] = av0.x;  As[lh + 1][lr] = av0.y;  As[lh + 2][lr] = av0.z;  As[lh + 3][lr] = av0.w;
    As[lh + 4][lr] = av1.x;  As[lh + 5][lr] = av1.y;  As[lh + 6][lr] = av1.z;  As[lh + 7][lr] = av1.w;
    As[lh + 8][lr] = av2.x;  As[lh + 9][lr] = av2.y;  As[lh + 10][lr] = av2.z; As[lh + 11][lr] = av2.w;
    As[lh + 12][lr] = av3.x; As[lh + 13][lr] = av3.y; As[lh + 14][lr] = av3.z; As[lh + 15][lr] = av3.w;
    Ws[lh + 0][lr] = wv0.x;  Ws[lh + 1][lr] = wv0.y;  Ws[lh + 2][lr] = wv0.z;  Ws[lh + 3][lr] = wv0.w;
    Ws[lh + 4][lr] = wv1.x;  Ws[lh + 5][lr] = wv1.y;  Ws[lh + 6][lr] = wv1.z;  Ws[lh + 7][lr] = wv1.w;
    Ws[lh + 8][lr] = wv2.x;  Ws[lh + 9][lr] = wv2.y;  Ws[lh + 10][lr] = wv2.z; Ws[lh + 11][lr] = wv2.w;
    Ws[lh + 12][lr] = wv3.x; Ws[lh + 13][lr] = wv3.y; Ws[lh + 14][lr] = wv3.z; Ws[lh + 15][lr] = wv3.w;
    __syncthreads();
#pragma unroll
    for (int kk = 0; kk < 32; kk++) {
      float4 a0 = *(const float4*)&As[kk][ty * 4];
      float4 a1 = *(const float4*)&As[kk][64 + ty * 4];
      float4 b0 = *(const float4*)&Ws[kk][tx * 4];
      float4 b1 = *(const float4*)&Ws[kk][64 + tx * 4];
      float a[8] = {a0.x, a0.y, a0.z, a0.w, a1.x, a1.y, a1.z, a1.w};
      float b[8] = {b0.x, b0.y, b0.z, b0.w, b1.x, b1.y, b1.z, b1.w};
#pragma unroll
      for (int i = 0; i < 8; i++)
#pragma unroll
        for (int j = 0; j < 8; j++) acc[i][j] = fmaf(a[i], b[j], acc[i][j]);
    }
  }

  float bv[8];
#pragma unroll
  for (int j = 0; j < 8; j++) {
    const int c = n0 + ((j >> 2) << 6) + tx * 4 + (j & 3);
    bv[j] = (MODE > 0) ? bias[c] : 0.f;
  }
#pragma unroll
  for (int i = 0; i < 8; i++) {
    const int r = m0 + ((i >> 2) << 6) + ty * 4 + (i & 3);
#pragma unroll
    for (int jg = 0; jg < 2; jg++) {
      float4 o;
      o.x = acc[i][jg * 4 + 0] + bv[jg * 4 + 0];
      o.y = acc[i][jg * 4 + 1] + bv[jg * 4 + 1];
      o.z = acc[i][jg * 4 + 2] + bv[jg * 4 + 2];
      o.w = acc[i][jg * 4 + 3] + bv[jg * 4 + 3];
      if (MODE == 2) {
        o.x = fmaxf(o.x, 0.f); o.y = fmaxf(o.y, 0.f);
        o.z = fmaxf(o.z, 0.f); o.w = fmaxf(o.w, 0.f);
      }
      *(float4*)&C[(i64)r * N + n0 + (jg << 6) + tx * 4] = o;
    }
  }
}

// ---------------- Attention: per-seq, 4 heads = 4 waves, lane = query t -------
template <int S, bool ISV2E>
__global__ __launch_bounds__(256) void attn_k(const float* __restrict__ QKV,
                                              const int* __restrict__ mask,
                                              float* __restrict__ O, int seq0) {
  __shared__ float QL[4][S][68];  // reused as O_lds after scores
  __shared__ float KL[4][S][68];
  __shared__ float VL[4][S][68];
  const int h = threadIdx.x >> 6, lane = threadIdx.x & 63;
  const int seq = blockIdx.x;
  const i64 base = (i64)seq * S;
  const int gseq = seq0 + seq;

#pragma unroll
  for (int t = 0; t < S; t++) {
    const float* row = QKV + (base + t) * 768 + h * 64 + lane;
    QL[h][t][lane] = row[0];
    KL[h][t][lane] = row[256];
    VL[h][t][lane] = row[512];
  }
  __syncthreads();

  if (lane < S) {
    const int t = lane;
    float q[64];
#pragma unroll
    for (int d4 = 0; d4 < 16; d4++) {
      float4 v = *(const float4*)&QL[h][t][d4 * 4];
      q[d4 * 4 + 0] = v.x; q[d4 * 4 + 1] = v.y;
      q[d4 * 4 + 2] = v.z; q[d4 * 4 + 3] = v.w;
    }
    float w[S];
    float mx = -1e30f;
#pragma unroll
    for (int s = 0; s < S; s++) {
      const bool valid = ISV2E ? (s == 0 || mask[(i64)gseq * ARITY + (s - 1)] != 0)
                               : (mask[(i64)gseq * S + s] != 0);
      float sc;
      if (valid) {
        sc = 0.f;
#pragma unroll
        for (int d4 = 0; d4 < 16; d4++) {
          float4 kv = *(const float4*)&KL[h][s][d4 * 4];
          sc = fmaf(q[d4 * 4 + 0], kv.x, sc);
          sc = fmaf(q[d4 * 4 + 1], kv.y, sc);
          sc = fmaf(q[d4 * 4 + 2], kv.z, sc);
          sc = fmaf(q[d4 * 4 + 3], kv.w, sc);
        }
        sc *= 0.125f;  // 1/sqrt(64)
      } else {
        sc = -1e9f;
      }
      w[s] = sc;
      mx = fmaxf(mx, sc);
    }
    float sum = 0.f;
#pragma unroll
    for (int s = 0; s < S; s++) { w[s] = __expf(w[s] - mx); sum += w[s]; }
    const float inv = 1.f / sum;
#pragma unroll
    for (int d4 = 0; d4 < 16; d4++) {
      float ox = 0.f, oy = 0.f, oz = 0.f, ow = 0.f;
#pragma unroll
      for (int s = 0; s < S; s++) {
        float4 vv = *(const float4*)&VL[h][s][d4 * 4];
        ox = fmaf(w[s], vv.x, ox); oy = fmaf(w[s], vv.y, oy);
        oz = fmaf(w[s], vv.z, oz); ow = fmaf(w[s], vv.w, ow);
      }
      float4 o; o.x = ox * inv; o.y = oy * inv; o.z = oz * inv; o.w = ow * inv;
      *(float4*)&QL[h][t][d4 * 4] = o;
    }
  }
  __syncthreads();
#pragma unroll
  for (int t = 0; t < S; t++)
    O[(base + t) * 256 + h * 64 + lane] = QL[h][t][lane];
}

// ------------- Fused: X = LN(X + P + bias) * g + b   (one wave per token) -----
__global__ __launch_bounds__(256) void ln_k(float* __restrict__ X,
                                            const float* __restrict__ P,
                                            const float* __restrict__ bias,
                                            const float* __restrict__ g,
                                            const float* __restrict__ b) {
  const int tok = blockIdx.x * 4 + (threadIdx.x >> 6);
  const int lane = threadIdx.x & 63;
  const i64 off = (i64)tok * 256 + lane * 4;
  float4 x = *(const float4*)&X[off];
  float4 p = *(const float4*)&P[off];
  float4 bb = *(const float4*)&bias[lane * 4];
  const float vx = x.x + p.x + bb.x, vy = x.y + p.y + bb.y;
  const float vz = x.z + p.z + bb.z, vw = x.w + p.w + bb.w;
  const float mean = wredsum(vx + vy + vz + vw) * (1.f / 256.f);
  const float dx = vx - mean, dy = vy - mean, dz = vz - mean, dw = vw - mean;
  const float var = wredsum(dx * dx + dy * dy + dz * dz + dw * dw) * (1.f / 256.f);
  const float rs = rsqrtf(var + 1e-5f);
  float4 g4 = *(const float4*)&g[lane * 4];
  float4 b4 = *(const float4*)&b[lane * 4];
  float4 o;
  o.x = dx * rs * g4.x + b4.x; o.y = dy * rs * g4.y + b4.y;
  o.z = dz * rs * g4.z + b4.z; o.w = dw * rs * g4.w + b4.w;
  *(float4*)&X[off] = o;
}

// ---------------- Gathers / scatters ------------------------------------------
__global__ __launch_bounds__(256) void gather_v2e_k(const float* __restrict__ unity,
                                                    const float* __restrict__ pos,
                                                    const int* __restrict__ xid,
                                                    const int* __restrict__ xpos,
                                                    float* __restrict__ X, int e0) {
  const int tk = blockIdx.x * 4 + (threadIdx.x >> 6);
  const int lane = threadIdx.x & 63;
  const int el = tk / SV, t = tk - el * SV;
  const int e = e0 + el;
  float4 v = make_float4(0.f, 0.f, 0.f, 0.f);
  if (t > 0) {
    const int id = xid[(i64)e * ARITY + (t - 1)];
    v = *(const float4*)&unity[(i64)id * 256 + lane * 4];
  }
  const int pp = xpos[(i64)e * SV + t];
  const float4 pv = *(const float4*)&pos[(i64)pp * 256 + lane * 4];
  v.x += pv.x; v.y += pv.y; v.z += pv.z; v.w += pv.w;
  *(float4*)&X[(i64)tk * 256 + lane * 4] = v;
}

__global__ __launch_bounds__(256) void gather_e2v_k(const float* __restrict__ ext,
                                                    const int* __restrict__ hid,
                                                    float* __restrict__ X, int n0) {
  const int tk = blockIdx.x * 4 + (threadIdx.x >> 6);
  const int lane = threadIdx.x & 63;
  const int nl = tk / SE, j = tk - nl * SE;
  const int n = n0 + nl;
  const int id = hid[(i64)n * SE + j];
  *(float4*)&X[(i64)tk * 256 + lane * 4] =
      *(const float4*)&ext[(i64)id * 256 + lane * 4];
}

__global__ __launch_bounds__(256) void extract_he_k(const float* __restrict__ X,
                                                    float* __restrict__ ext, int e0) {
  const int el = blockIdx.x * 4 + (threadIdx.x >> 6);
  const int lane = threadIdx.x & 63;
  *(float4*)&ext[(i64)(e0 + el) * 256 + lane * 4] =
      *(const float4*)&X[(i64)el * SV * 256 + lane * 4];
}

__global__ __launch_bounds__(256) void scatter_k(const float* __restrict__ X,
                                                 const int* __restrict__ subg,
                                                 float* __restrict__ unity, int n0) {
  const int nl = blockIdx.x * 4 + (threadIdx.x >> 6);
  const int lane = threadIdx.x & 63;
  const int dst = subg[n0 + nl];
  *(float4*)&unity[(i64)dst * 256 + lane * 4] =
      *(const float4*)&X[(i64)nl * SE * 256 + lane * 4];
}

__global__ __launch_bounds__(256) void ext_init_k(float* __restrict__ ext,
                                                  const float* __restrict__ pad,
                                                  const float* __restrict__ cls) {
  const int d = threadIdx.x;
  ext[(i64)NHEDGE * 256 + d] = pad[d];
  ext[(i64)(NHEDGE + 1) * 256 + d] = cls[d];
}

__global__ __launch_bounds__(256) void out_gather_k(const float* __restrict__ ext,
                                                    const int* __restrict__ pred,
                                                    float* __restrict__ out) {
  const int i = blockIdx.x * 4 + (threadIdx.x >> 6);
  const int lane = threadIdx.x & 63;
  const int e = pred[i];
  *(float4*)&out[(i64)i * 256 + lane * 4] =
      *(const float4*)&ext[(i64)e * 256 + lane * 4];
}

// ---------------- Host orchestration ------------------------------------------
extern "C" void kernel_launch(void* const* d_in, const int* in_sizes, int n_in,
                              void* d_out, int out_size, void* d_ws, size_t ws_size,
                              hipStream_t stream) {
  (void)in_sizes; (void)n_in; (void)out_size;
  const float* unity_in = (const float*)d_in[0];
  const float* cls_emb  = (const float*)d_in[1];
  const float* pad_emb  = (const float*)d_in[2];
  const float* pos_tab  = (const float*)d_in[3];
  const float* qkv_w    = (const float*)d_in[4];
  const float* qkv_b    = (const float*)d_in[5];
  const float* out_w    = (const float*)d_in[6];
  const float* out_b    = (const float*)d_in[7];
  const float* ln1_g    = (const float*)d_in[8];
  const float* ln1_b    = (const float*)d_in[9];
  const float* ln2_g    = (const float*)d_in[10];
  const float* ln2_b    = (const float*)d_in[11];
  const float* ff1_w    = (const float*)d_in[12];
  const float* ff1_b    = (const float*)d_in[13];
  const float* ff2_w    = (const float*)d_in[14];
  const float* ff2_b    = (const float*)d_in[15];
  const int* xid   = (const int*)d_in[16];
  const int* vmask = (const int*)d_in[17];
  const int* xpos  = (const int*)d_in[18];
  const int* hid   = (const int*)d_in[19];
  const int* hmask = (const int*)d_in[20];
  const int* subg  = (const int*)d_in[21];
  const int* pred  = (const int*)d_in[22];

  // ---- workspace layout, adaptive to ws_size ----
  const i64 unity_b = (i64)NTOTAL * 256 * 4;         // 102.4 MB
  const i64 ext_b   = (i64)(NHEDGE + 2) * 256 * 4;   // 33.6 MB
  // per-chunk-element bytes: SE tokens * (X:1024 + Y:4096 + O:1024 + P:1024)
  const i64 per_elem = (i64)SE * (1024 + 4096 + 1024 + 1024);
  int CHUNK = 8192;
  while (CHUNK > 128 && unity_b + ext_b + (i64)CHUNK * per_elem > (i64)ws_size)
    CHUNK >>= 1;

  char* w = (char*)d_ws;
  float* unity = (float*)w; w += unity_b;
  float* ext   = (float*)w; w += ext_b;
  float* X     = (float*)w; w += (i64)CHUNK * SE * 256 * 4;
  float* Y     = (float*)w; w += (i64)CHUNK * SE * 1024 * 4;
  float* O     = (float*)w; w += (i64)CHUNK * SE * 256 * 4;
  float* P     = (float*)w; w += (i64)CHUNK * SE * 256 * 4;

  hipMemcpyAsync(unity, unity_in, unity_b, hipMemcpyDeviceToDevice, stream);
  ext_init_k<<<1, 256, 0, stream>>>(ext, pad_emb, cls_emb);

  for (int k = 0; k <= 2; k++) {
    // ---- V2E ----
    for (int c = 0; c < NHEDGE / CHUNK; c++) {
      const int e0 = c * CHUNK;
      const int M = CHUNK * SV;
      gather_v2e_k<<<M / 4, 256, 0, stream>>>(unity, pos_tab, xid, xpos, X, e0);
      for (int l = 0; l < 2; l++) {
        gemm_k<256, 1><<<dim3(6, M / 128), 256, 0, stream>>>(
            X, qkv_w + (i64)l * 768 * 256, qkv_b + l * 768, Y, M, 768);
        attn_k<SV, true><<<CHUNK, 256, 0, stream>>>(Y, vmask, O, e0);
        gemm_k<256, 0><<<dim3(2, M / 128), 256, 0, stream>>>(
            O, out_w + (i64)l * 256 * 256, nullptr, P, M, 256);
        ln_k<<<M / 4, 256, 0, stream>>>(X, P, out_b + l * 256, ln1_g + l * 256,
                                        ln1_b + l * 256);
        gemm_k<256, 2><<<dim3(8, M / 128), 256, 0, stream>>>(
            X, ff1_w + (i64)l * 1024 * 256, ff1_b + l * 1024, Y, M, 1024);
        gemm_k<1024, 0><<<dim3(2, M / 128), 256, 0, stream>>>(
            Y, ff2_w + (i64)l * 256 * 1024, nullptr, P, M, 256);
        ln_k<<<M / 4, 256, 0, stream>>>(X, P, ff2_b + l * 256, ln2_g + l * 256,
                                        ln2_b + l * 256);
      }
      extract_he_k<<<CHUNK / 4, 256, 0, stream>>>(X, ext, e0);
    }
    // ---- E2V ----
    if (k < 2) {
      for (int c = 0; c < NNODE / CHUNK; c++) {
        const int n0 = c * CHUNK;
        const int M = CHUNK * SE;
        gather_e2v_k<<<M / 4, 256, 0, stream>>>(ext, hid, X, n0);
        for (int l = 0; l < 2; l++) {
          gemm_k<256, 1><<<dim3(6, M / 128), 256, 0, stream>>>(
              X, qkv_w + (i64)l * 768 * 256, qkv_b + l * 768, Y, M, 768);
          attn_k<SE, false><<<CHUNK, 256, 0, stream>>>(Y, hmask, O, n0);
          gemm_k<256, 0><<<dim3(2, M / 128), 256, 0, stream>>>(
              O, out_w + (i64)l * 256 * 256, nullptr, P, M, 256);
          ln_k<<<M / 4, 256, 0, stream>>>(X, P, out_b + l * 256, ln1_g + l * 256,
                                          ln1_b + l * 256);
          gemm_k<256, 2><<<dim3(8, M / 128), 256, 0, stream>>>(
              X, ff1_w + (i64)l * 1024 * 256, ff1_b + l * 1024, Y, M, 1024);
          gemm_k<1024, 0><<<dim3(2, M / 128), 256, 0, stream>>>(
              Y, ff2_w + (i64)l * 256 * 1024, nullptr, P, M, 256);
          ln_k<<<M / 4, 256, 0, stream>>>(X, P, ff2_b + l * 256, ln2_g + l * 256,
                                          ln2_b + l * 256);
        }
        scatter_k<<<CHUNK / 4, 256, 0, stream>>>(X, subg, unity, n0);
      }
    }
  }
  out_gather_k<<<64, 256, 0, stream>>>(ext, pred, (float*)d_out);
}

// Round 3
// 33647.769 us; speedup vs baseline: 4.6192x; 4.6192x over previous
//
#include <hip/hip_runtime.h>
#include <stdint.h>

typedef long long i64;
typedef __attribute__((ext_vector_type(8))) short bf16x8;
typedef __attribute__((ext_vector_type(4))) float f32x4;

#define SV 11
#define SE 17
#define ARITY 10
#define NHEDGE 32768
#define NNODE 65536
#define NTOTAL 100000

__device__ __forceinline__ float wredsum(float s) {
#pragma unroll
  for (int o = 32; o > 0; o >>= 1) s += __shfl_xor(s, o, 64);
  return s;
}

__device__ __forceinline__ float b2f(ushort u) {
  union { uint32_t i; float f; } v; v.i = (uint32_t)u << 16; return v.f;
}
__device__ __forceinline__ ushort f2b(float f) {
  union { float f; uint32_t i; } v; v.f = f;
  uint32_t u = v.i + 0x7fffu + ((v.i >> 16) & 1u);
  return (ushort)(u >> 16);
}

__device__ __forceinline__ void gload_lds16(const void* g, void* l) {
  __builtin_amdgcn_global_load_lds((const __attribute__((address_space(1))) void*)g,
                                   (__attribute__((address_space(3))) void*)l, 16, 0, 0);
}

// -------- bf16 MFMA GEMM: C[M,N] = act(A[M,K] @ W[N,K]^T + bias) --------------
// MODE: 0 = none, 1 = +bias, 2 = +bias+relu.  Tile 128x128, BK=64, 4 waves.
// LDS layout: [row][kblk16] with kblk XOR-swizzled by (row&7); global_load_lds
// writes linearly, so the swizzle is applied on the global SOURCE address
// (write side) and re-applied on the ds_read (read side) — same involution.
template <int K, int MODE>
__global__ __launch_bounds__(256) void gemm_bf16_k(const ushort* __restrict__ A,
                                                   const ushort* __restrict__ W,
                                                   const float* __restrict__ bias,
                                                   ushort* __restrict__ C, int M, int N) {
  __shared__ ushort As[128 * 64];
  __shared__ ushort Ws[128 * 64];
  const int tid = threadIdx.x;
  const int wave = tid >> 6, lane = tid & 63;
  const int m0 = blockIdx.y << 7, n0 = blockIdx.x << 7;
  const int wr = wave >> 1, wc = wave & 1;

  f32x4 acc[4][4];
#pragma unroll
  for (int m = 0; m < 4; m++)
#pragma unroll
    for (int n = 0; n < 4; n++) acc[m][n] = (f32x4){0.f, 0.f, 0.f, 0.f};

  // staging: wave covers tile rows [wave*32, wave*32+32), 4 calls of 1KB each.
  // lane covers row base+ (lane>>3), 16B-block (lane&7); global block index is
  // pre-swizzled: kblk_g = (lane&7) ^ (row&7) with row&7 == lane>>3 here.
  const int srow = (wave << 5) + (lane >> 3);
  const int kblk_g = (lane & 7) ^ (lane >> 3);
  const ushort* Ag = A + (i64)(m0 + srow) * K + (kblk_g << 3);
  const ushort* Wg = W + (i64)(n0 + srow) * K + (kblk_g << 3);
  char* lA = (char*)As + (wave << 12);
  char* lB = (char*)Ws + (wave << 12);

  for (int k0 = 0; k0 < K; k0 += 64) {
#pragma unroll
    for (int i = 0; i < 4; i++) {
      gload_lds16(Ag + k0 + (i64)(i * 8) * K, lA + i * 1024);
      gload_lds16(Wg + k0 + (i64)(i * 8) * K, lB + i * 1024);
    }
    __syncthreads();  // barrier drains vmcnt -> staged data visible
#pragma unroll
    for (int kh = 0; kh < 2; kh++) {
      const int kb = (kh << 2) + (lane >> 4);     // global 16B-block within BK
      const int kbl = (kb ^ (lane & 7)) << 3;     // swizzled element offset
      bf16x8 af[4], bf[4];
#pragma unroll
      for (int m = 0; m < 4; m++) {
        const int row = (wr << 6) + (m << 4) + (lane & 15);
        af[m] = *(const bf16x8*)&As[row * 64 + kbl];
      }
#pragma unroll
      for (int n = 0; n < 4; n++) {
        const int row = (wc << 6) + (n << 4) + (lane & 15);
        bf[n] = *(const bf16x8*)&Ws[row * 64 + kbl];
      }
#pragma unroll
      for (int m = 0; m < 4; m++)
#pragma unroll
        for (int n = 0; n < 4; n++)
          acc[m][n] = __builtin_amdgcn_mfma_f32_16x16x32_bf16(af[m], bf[n], acc[m][n], 0, 0, 0);
    }
    __syncthreads();  // all waves done reading before next stage overwrites
  }

#pragma unroll
  for (int n = 0; n < 4; n++) {
    const int col = n0 + (wc << 6) + (n << 4) + (lane & 15);
    const float bv = (MODE > 0) ? bias[col] : 0.f;
#pragma unroll
    for (int m = 0; m < 4; m++) {
      const int rb = m0 + (wr << 6) + (m << 4) + ((lane >> 4) << 2);
#pragma unroll
      for (int j = 0; j < 4; j++) {
        float v = acc[m][n][j] + bv;
        if (MODE == 2) v = fmaxf(v, 0.f);
        C[(i64)(rb + j) * N + col] = f2b(v);
      }
    }
  }
}

// ---------------- Attention: per-seq, 4 heads = 4 waves, lane = query t -------
template <int S, bool ISV2E>
__global__ __launch_bounds__(256) void attn_k(const ushort* __restrict__ QKV,
                                              const int* __restrict__ mask,
                                              ushort* __restrict__ O, int seq0) {
  __shared__ float QL[4][S][68];
  __shared__ float KL[4][S][68];
  __shared__ float VL[4][S][68];
  const int h = threadIdx.x >> 6, lane = threadIdx.x & 63;
  const int seq = blockIdx.x;
  const i64 base = (i64)seq * S;
  const int gseq = seq0 + seq;

#pragma unroll
  for (int t = 0; t < S; t++) {
    const ushort* row = QKV + (base + t) * 768 + h * 64 + lane;
    QL[h][t][lane] = b2f(row[0]);
    KL[h][t][lane] = b2f(row[256]);
    VL[h][t][lane] = b2f(row[512]);
  }
  __syncthreads();

  if (lane < S) {
    const int t = lane;
    float q[64];
#pragma unroll
    for (int d4 = 0; d4 < 16; d4++) {
      float4 v = *(const float4*)&QL[h][t][d4 * 4];
      q[d4 * 4 + 0] = v.x; q[d4 * 4 + 1] = v.y;
      q[d4 * 4 + 2] = v.z; q[d4 * 4 + 3] = v.w;
    }
    float w[S];
    float mx = -1e30f;
#pragma unroll
    for (int s = 0; s < S; s++) {
      const bool valid = ISV2E ? (s == 0 || mask[(i64)gseq * ARITY + (s - 1)] != 0)
                               : (mask[(i64)gseq * S + s] != 0);
      float sc;
      if (valid) {
        sc = 0.f;
#pragma unroll
        for (int d4 = 0; d4 < 16; d4++) {
          float4 kv = *(const float4*)&KL[h][s][d4 * 4];
          sc = fmaf(q[d4 * 4 + 0], kv.x, sc);
          sc = fmaf(q[d4 * 4 + 1], kv.y, sc);
          sc = fmaf(q[d4 * 4 + 2], kv.z, sc);
          sc = fmaf(q[d4 * 4 + 3], kv.w, sc);
        }
        sc *= 0.125f;
      } else {
        sc = -1e9f;
      }
      w[s] = sc;
      mx = fmaxf(mx, sc);
    }
    float sum = 0.f;
#pragma unroll
    for (int s = 0; s < S; s++) { w[s] = __expf(w[s] - mx); sum += w[s]; }
    const float inv = 1.f / sum;
#pragma unroll
    for (int d4 = 0; d4 < 16; d4++) {
      float ox = 0.f, oy = 0.f, oz = 0.f, ow = 0.f;
#pragma unroll
      for (int s = 0; s < S; s++) {
        float4 vv = *(const float4*)&VL[h][s][d4 * 4];
        ox = fmaf(w[s], vv.x, ox); oy = fmaf(w[s], vv.y, oy);
        oz = fmaf(w[s], vv.z, oz); ow = fmaf(w[s], vv.w, ow);
      }
      float4 o; o.x = ox * inv; o.y = oy * inv; o.z = oz * inv; o.w = ow * inv;
      *(float4*)&QL[h][t][d4 * 4] = o;
    }
  }
  __syncthreads();
#pragma unroll
  for (int t = 0; t < S; t++)
    O[(base + t) * 256 + h * 64 + lane] = f2b(QL[h][t][lane]);
}

// ------------- Fused: X = LN(X + P + bias) * g + b   (one wave per token) -----
__global__ __launch_bounds__(256) void ln_k(ushort* __restrict__ X,
                                            const ushort* __restrict__ P,
                                            const float* __restrict__ bias,
                                            const float* __restrict__ g,
                                            const float* __restrict__ b) {
  const int tok = blockIdx.x * 4 + (threadIdx.x >> 6);
  const int lane = threadIdx.x & 63;
  const i64 off = (i64)tok * 256 + lane * 4;
  ushort4 xu = *(const ushort4*)&X[off];
  ushort4 pu = *(const ushort4*)&P[off];
  float4 bb = *(const float4*)&bias[lane * 4];
  const float vx = b2f(xu.x) + b2f(pu.x) + bb.x;
  const float vy = b2f(xu.y) + b2f(pu.y) + bb.y;
  const float vz = b2f(xu.z) + b2f(pu.z) + bb.z;
  const float vw = b2f(xu.w) + b2f(pu.w) + bb.w;
  const float mean = wredsum(vx + vy + vz + vw) * (1.f / 256.f);
  const float dx = vx - mean, dy = vy - mean, dz = vz - mean, dw = vw - mean;
  const float var = wredsum(dx * dx + dy * dy + dz * dz + dw * dw) * (1.f / 256.f);
  const float rs = rsqrtf(var + 1e-5f);
  float4 g4 = *(const float4*)&g[lane * 4];
  float4 b4 = *(const float4*)&b[lane * 4];
  ushort4 o;
  o.x = f2b(dx * rs * g4.x + b4.x); o.y = f2b(dy * rs * g4.y + b4.y);
  o.z = f2b(dz * rs * g4.z + b4.z); o.w = f2b(dw * rs * g4.w + b4.w);
  *(ushort4*)&X[off] = o;
}

// ---------------- Gathers / scatters / conversion -----------------------------
__global__ __launch_bounds__(256) void f2b_cvt_k(const float* __restrict__ in,
                                                 ushort* __restrict__ out, int n) {
  for (int i = blockIdx.x * 256 + threadIdx.x; i < n; i += gridDim.x * 256)
    out[i] = f2b(in[i]);
}

__global__ __launch_bounds__(256) void gather_v2e_k(const float* __restrict__ unity,
                                                    const float* __restrict__ pos,
                                                    const int* __restrict__ xid,
                                                    const int* __restrict__ xpos,
                                                    ushort* __restrict__ X, int e0) {
  const int tk = blockIdx.x * 4 + (threadIdx.x >> 6);
  const int lane = threadIdx.x & 63;
  const int el = tk / SV, t = tk - el * SV;
  const int e = e0 + el;
  float4 v = make_float4(0.f, 0.f, 0.f, 0.f);
  if (t > 0) {
    const int id = xid[(i64)e * ARITY + (t - 1)];
    v = *(const float4*)&unity[(i64)id * 256 + lane * 4];
  }
  const int pp = xpos[(i64)e * SV + t];
  const float4 pv = *(const float4*)&pos[(i64)pp * 256 + lane * 4];
  ushort4 o;
  o.x = f2b(v.x + pv.x); o.y = f2b(v.y + pv.y);
  o.z = f2b(v.z + pv.z); o.w = f2b(v.w + pv.w);
  *(ushort4*)&X[(i64)tk * 256 + lane * 4] = o;
}

__global__ __launch_bounds__(256) void gather_e2v_k(const ushort* __restrict__ ext,
                                                    const int* __restrict__ hid,
                                                    ushort* __restrict__ X, int n0) {
  const int tk = blockIdx.x * 4 + (threadIdx.x >> 6);
  const int lane = threadIdx.x & 63;
  const int nl = tk / SE, j = tk - nl * SE;
  const int n = n0 + nl;
  const int id = hid[(i64)n * SE + j];
  *(uint2*)&X[(i64)tk * 256 + lane * 4] =
      *(const uint2*)&ext[(i64)id * 256 + lane * 4];
}

__global__ __launch_bounds__(256) void extract_he_k(const ushort* __restrict__ X,
                                                    ushort* __restrict__ ext, int e0) {
  const int el = blockIdx.x * 4 + (threadIdx.x >> 6);
  const int lane = threadIdx.x & 63;
  *(uint2*)&ext[(i64)(e0 + el) * 256 + lane * 4] =
      *(const uint2*)&X[(i64)el * SV * 256 + lane * 4];
}

__global__ __launch_bounds__(256) void scatter_k(const ushort* __restrict__ X,
                                                 const int* __restrict__ subg,
                                                 float* __restrict__ unity, int n0) {
  const int nl = blockIdx.x * 4 + (threadIdx.x >> 6);
  const int lane = threadIdx.x & 63;
  const int dst = subg[n0 + nl];
  ushort4 v = *(const ushort4*)&X[(i64)nl * SE * 256 + lane * 4];
  float4 o; o.x = b2f(v.x); o.y = b2f(v.y); o.z = b2f(v.z); o.w = b2f(v.w);
  *(float4*)&unity[(i64)dst * 256 + lane * 4] = o;
}

__global__ __launch_bounds__(256) void ext_init_k(ushort* __restrict__ ext,
                                                  const float* __restrict__ pad,
                                                  const float* __restrict__ cls) {
  const int d = threadIdx.x;
  ext[(i64)NHEDGE * 256 + d] = f2b(pad[d]);
  ext[(i64)(NHEDGE + 1) * 256 + d] = f2b(cls[d]);
}

__global__ __launch_bounds__(256) void out_gather_k(const ushort* __restrict__ ext,
                                                    const int* __restrict__ pred,
                                                    float* __restrict__ out) {
  const int i = blockIdx.x * 4 + (threadIdx.x >> 6);
  const int lane = threadIdx.x & 63;
  const int e = pred[i];
  ushort4 v = *(const ushort4*)&ext[(i64)e * 256 + lane * 4];
  float4 o; o.x = b2f(v.x); o.y = b2f(v.y); o.z = b2f(v.z); o.w = b2f(v.w);
  *(float4*)&out[(i64)i * 256 + lane * 4] = o;
}

// ---------------- Host orchestration ------------------------------------------
extern "C" void kernel_launch(void* const* d_in, const int* in_sizes, int n_in,
                              void* d_out, int out_size, void* d_ws, size_t ws_size,
                              hipStream_t stream) {
  (void)in_sizes; (void)n_in; (void)out_size;
  const float* unity_in = (const float*)d_in[0];
  const float* cls_emb  = (const float*)d_in[1];
  const float* pad_emb  = (const float*)d_in[2];
  const float* pos_tab  = (const float*)d_in[3];
  const float* qkv_w    = (const float*)d_in[4];
  const float* qkv_b    = (const float*)d_in[5];
  const float* out_w    = (const float*)d_in[6];
  const float* out_b    = (const float*)d_in[7];
  const float* ln1_g    = (const float*)d_in[8];
  const float* ln1_b    = (const float*)d_in[9];
  const float* ln2_g    = (const float*)d_in[10];
  const float* ln2_b    = (const float*)d_in[11];
  const float* ff1_w    = (const float*)d_in[12];
  const float* ff1_b    = (const float*)d_in[13];
  const float* ff2_w    = (const float*)d_in[14];
  const float* ff2_b    = (const float*)d_in[15];
  const int* xid   = (const int*)d_in[16];
  const int* vmask = (const int*)d_in[17];
  const int* xpos  = (const int*)d_in[18];
  const int* hid   = (const int*)d_in[19];
  const int* hmask = (const int*)d_in[20];
  const int* subg  = (const int*)d_in[21];
  const int* pred  = (const int*)d_in[22];

  // ---- workspace layout (adaptive CHUNK) ----
  const i64 unity_b = (i64)NTOTAL * 256 * 4;          // fp32, 102.4 MB
  const i64 ext_b   = (i64)(NHEDGE + 2) * 256 * 2;    // bf16, 16.8 MB
  const int nq = 2 * 768 * 256, no = 2 * 256 * 256,
            n1 = 2 * 1024 * 256, n2 = 2 * 256 * 1024;
  const i64 wts_b = (i64)(nq + no + n1 + n2) * 2;     // 3.1 MB
  const i64 per_elem = (i64)SE * (512 + 2048 + 512 + 512);  // X+Y+O+P bytes
  int CHUNK = 8192;
  while (CHUNK > 128 && unity_b + ext_b + wts_b + (i64)CHUNK * per_elem > (i64)ws_size)
    CHUNK >>= 1;

  char* w = (char*)d_ws;
  float*  unity = (float*)w;  w += unity_b;
  ushort* ext   = (ushort*)w; w += ext_b;
  ushort* wq    = (ushort*)w; w += (i64)nq * 2;
  ushort* wo    = (ushort*)w; w += (i64)no * 2;
  ushort* w1    = (ushort*)w; w += (i64)n1 * 2;
  ushort* w2    = (ushort*)w; w += (i64)n2 * 2;
  ushort* X     = (ushort*)w; w += (i64)CHUNK * SE * 256 * 2;
  ushort* Y     = (ushort*)w; w += (i64)CHUNK * SE * 1024 * 2;
  ushort* O     = (ushort*)w; w += (i64)CHUNK * SE * 256 * 2;
  ushort* P     = (ushort*)w; w += (i64)CHUNK * SE * 256 * 2;

  f2b_cvt_k<<<512, 256, 0, stream>>>(qkv_w, wq, nq);
  f2b_cvt_k<<<512, 256, 0, stream>>>(out_w, wo, no);
  f2b_cvt_k<<<512, 256, 0, stream>>>(ff1_w, w1, n1);
  f2b_cvt_k<<<512, 256, 0, stream>>>(ff2_w, w2, n2);
  hipMemcpyAsync(unity, unity_in, unity_b, hipMemcpyDeviceToDevice, stream);
  ext_init_k<<<1, 256, 0, stream>>>(ext, pad_emb, cls_emb);

  for (int k = 0; k <= 2; k++) {
    // ---- V2E ----
    for (int c = 0; c < NHEDGE / CHUNK; c++) {
      const int e0 = c * CHUNK;
      const int M = CHUNK * SV;
      gather_v2e_k<<<M / 4, 256, 0, stream>>>(unity, pos_tab, xid, xpos, X, e0);
      for (int l = 0; l < 2; l++) {
        gemm_bf16_k<256, 1><<<dim3(6, M / 128), 256, 0, stream>>>(
            X, wq + (i64)l * 768 * 256, qkv_b + l * 768, Y, M, 768);
        attn_k<SV, true><<<CHUNK, 256, 0, stream>>>(Y, vmask, O, e0);
        gemm_bf16_k<256, 0><<<dim3(2, M / 128), 256, 0, stream>>>(
            O, wo + (i64)l * 256 * 256, nullptr, P, M, 256);
        ln_k<<<M / 4, 256, 0, stream>>>(X, P, out_b + l * 256, ln1_g + l * 256,
                                        ln1_b + l * 256);
        gemm_bf16_k<256, 2><<<dim3(8, M / 128), 256, 0, stream>>>(
            X, w1 + (i64)l * 1024 * 256, ff1_b + l * 1024, Y, M, 1024);
        gemm_bf16_k<1024, 0><<<dim3(2, M / 128), 256, 0, stream>>>(
            Y, w2 + (i64)l * 256 * 1024, nullptr, P, M, 256);
        ln_k<<<M / 4, 256, 0, stream>>>(X, P, ff2_b + l * 256, ln2_g + l * 256,
                                        ln2_b + l * 256);
      }
      extract_he_k<<<CHUNK / 4, 256, 0, stream>>>(X, ext, e0);
    }
    // ---- E2V ----
    if (k < 2) {
      for (int c = 0; c < NNODE / CHUNK; c++) {
        const int n0 = c * CHUNK;
        const int M = CHUNK * SE;
        gather_e2v_k<<<M / 4, 256, 0, stream>>>(ext, hid, X, n0);
        for (int l = 0; l < 2; l++) {
          gemm_bf16_k<256, 1><<<dim3(6, M / 128), 256, 0, stream>>>(
              X, wq + (i64)l * 768 * 256, qkv_b + l * 768, Y, M, 768);
          attn_k<SE, false><<<CHUNK, 256, 0, stream>>>(Y, hmask, O, n0);
          gemm_bf16_k<256, 0><<<dim3(2, M / 128), 256, 0, stream>>>(
              O, wo + (i64)l * 256 * 256, nullptr, P, M, 256);
          ln_k<<<M / 4, 256, 0, stream>>>(X, P, out_b + l * 256, ln1_g + l * 256,
                                          ln1_b + l * 256);
          gemm_bf16_k<256, 2><<<dim3(8, M / 128), 256, 0, stream>>>(
              X, w1 + (i64)l * 1024 * 256, ff1_b + l * 1024, Y, M, 1024);
          gemm_bf16_k<1024, 0><<<dim3(2, M / 128), 256, 0, stream>>>(
              Y, w2 + (i64)l * 256 * 1024, nullptr, P, M, 256);
          ln_k<<<M / 4, 256, 0, stream>>>(X, P, ff2_b + l * 256, ln2_g + l * 256,
                                          ln2_b + l * 256);
        }
        scatter_k<<<CHUNK / 4, 256, 0, stream>>>(X, subg, unity, n0);
      }
    }
  }
  out_gather_k<<<64, 256, 0, stream>>>(ext, pred, (float*)d_out);
}

// Round 4
// 33478.406 us; speedup vs baseline: 4.6425x; 1.0051x over previous
//
#include <hip/hip_runtime.h>
#include <stdint.h>

typedef long long i64;
typedef __attribute__((ext_vector_type(8))) short bf16x8;
typedef __attribute__((ext_vector_type(4))) float f32x4;

#define SV 11
#define SE 17
#define ARITY 10
#define NHEDGE 32768
#define NNODE 65536
#define NTOTAL 100000

__device__ __forceinline__ float wredsum(float s) {
#pragma unroll
  for (int o = 32; o > 0; o >>= 1) s += __shfl_xor(s, o, 64);
  return s;
}

__device__ __forceinline__ float b2f(ushort u) {
  union { uint32_t i; float f; } v; v.i = (uint32_t)u << 16; return v.f;
}
__device__ __forceinline__ ushort f2b(float f) {
  union { float f; uint32_t i; } v; v.f = f;
  uint32_t u = v.i + 0x7fffu + ((v.i >> 16) & 1u);
  return (ushort)(u >> 16);
}
__device__ __forceinline__ uint pack2(float a, float b) {
  return (uint)f2b(a) | ((uint)f2b(b) << 16);
}

__device__ __forceinline__ void gload_lds16(const void* g, void* l) {
  __builtin_amdgcn_global_load_lds((const __attribute__((address_space(1))) void*)g,
                                   (__attribute__((address_space(3))) void*)l, 16, 0, 0);
}

// -------- bf16 MFMA GEMM: C[M,N] = act(A[M,K] @ W[N,K]^T + bias) --------------
// MODE: 0 = none, 1 = +bias, 2 = +bias+relu.  Tile 128x128, BK=64, 4 waves.
// Swapped-operand MFMA: mfma(bf, af) puts 4 CONSECUTIVE output columns of one
// token in each lane's 4 acc regs -> 8B packed stores (16/thread, not 64).
template <int K, int MODE>
__global__ __launch_bounds__(256) void gemm_bf16_k(const ushort* __restrict__ A,
                                                   const ushort* __restrict__ W,
                                                   const float* __restrict__ bias,
                                                   ushort* __restrict__ C, int M, int N) {
  __shared__ ushort As[128 * 64];
  __shared__ ushort Ws[128 * 64];
  const int tid = threadIdx.x;
  const int wave = tid >> 6, lane = tid & 63;
  const int m0 = blockIdx.y << 7, n0 = blockIdx.x << 7;
  const int wr = wave >> 1, wc = wave & 1;

  f32x4 acc[4][4];
#pragma unroll
  for (int m = 0; m < 4; m++)
#pragma unroll
    for (int n = 0; n < 4; n++) acc[m][n] = (f32x4){0.f, 0.f, 0.f, 0.f};

  const int srow = (wave << 5) + (lane >> 3);
  const int kblk_g = (lane & 7) ^ (lane >> 3);
  const ushort* Ag = A + (i64)(m0 + srow) * K + (kblk_g << 3);
  const ushort* Wg = W + (i64)(n0 + srow) * K + (kblk_g << 3);
  char* lA = (char*)As + (wave << 12);
  char* lB = (char*)Ws + (wave << 12);

  for (int k0 = 0; k0 < K; k0 += 64) {
#pragma unroll
    for (int i = 0; i < 4; i++) {
      gload_lds16(Ag + k0 + (i64)(i * 8) * K, lA + i * 1024);
      gload_lds16(Wg + k0 + (i64)(i * 8) * K, lB + i * 1024);
    }
    __syncthreads();
#pragma unroll
    for (int kh = 0; kh < 2; kh++) {
      const int kb = (kh << 2) + (lane >> 4);
      bf16x8 af[4], bf[4];
#pragma unroll
      for (int m = 0; m < 4; m++) {
        const int row = (wr << 6) + (m << 4) + (lane & 15);
        af[m] = *(const bf16x8*)&As[row * 64 + ((kb ^ (row & 7)) << 3)];
      }
#pragma unroll
      for (int n = 0; n < 4; n++) {
        const int row = (wc << 6) + (n << 4) + (lane & 15);
        bf[n] = *(const bf16x8*)&Ws[row * 64 + ((kb ^ (row & 7)) << 3)];
      }
#pragma unroll
      for (int m = 0; m < 4; m++)
#pragma unroll
        for (int n = 0; n < 4; n++)
          acc[m][n] = __builtin_amdgcn_mfma_f32_16x16x32_bf16(bf[n], af[m], acc[m][n], 0, 0, 0);
    }
    __syncthreads();
  }

#pragma unroll
  for (int m = 0; m < 4; m++) {
    const int row = m0 + (wr << 6) + (m << 4) + (lane & 15);
#pragma unroll
    for (int n = 0; n < 4; n++) {
      const int col = n0 + (wc << 6) + (n << 4) + ((lane >> 4) << 2);
      float v0 = acc[m][n][0], v1 = acc[m][n][1], v2 = acc[m][n][2], v3 = acc[m][n][3];
      if (MODE > 0) {
        const f32x4 bv = *(const f32x4*)&bias[col];
        v0 += bv[0]; v1 += bv[1]; v2 += bv[2]; v3 += bv[3];
      }
      if (MODE == 2) {
        v0 = fmaxf(v0, 0.f); v1 = fmaxf(v1, 0.f);
        v2 = fmaxf(v2, 0.f); v3 = fmaxf(v3, 0.f);
      }
      uint2 o; o.x = pack2(v0, v1); o.y = pack2(v2, v3);
      *(uint2*)&C[(i64)row * N + col] = o;
    }
  }
}

// -------- Fused GEMM + residual + LayerNorm (N = 256 fixed) -------------------
// C/X = LN(R + A@W^T + bias) * g + b.   Tile 128x256, 8 waves (2r x 4c).
// R and C may alias (in-place): each (token,col4) unit is owned by one thread.
template <int K>
__global__ __launch_bounds__(512) void gemm_ln_k(const ushort* __restrict__ A,
                                                 const ushort* __restrict__ W,
                                                 const float* __restrict__ bias,
                                                 const ushort* R,
                                                 const float* __restrict__ g,
                                                 const float* __restrict__ b,
                                                 ushort* C, int M) {
  __shared__ ushort As[128 * 64];
  __shared__ ushort Ws[256 * 64];
  __shared__ float partS[128][4];
  __shared__ float partQ[128][4];
  const int tid = threadIdx.x;
  const int wave = tid >> 6, lane = tid & 63;
  const int m0 = blockIdx.x << 7;
  const int wr = wave >> 2, wc = wave & 3;

  f32x4 acc[4][4];
#pragma unroll
  for (int m = 0; m < 4; m++)
#pragma unroll
    for (int n = 0; n < 4; n++) acc[m][n] = (f32x4){0.f, 0.f, 0.f, 0.f};

  // staging maps (wave-uniform-base + lane*16 LDS dest; swizzle on global src)
  // A: 1024 16B-units, 2 per thread; W: 2048 units, 4 per thread.
  int rowA[2], kgA[2];
#pragma unroll
  for (int i = 0; i < 2; i++) {
    const int u = wave * 128 + i * 64 + lane;
    rowA[i] = u >> 3; kgA[i] = (u & 7) ^ ((u >> 3) & 7);
  }
  int rowW[4], kgW[4];
#pragma unroll
  for (int i = 0; i < 4; i++) {
    const int u = wave * 256 + i * 64 + lane;
    rowW[i] = u >> 3; kgW[i] = (u & 7) ^ ((u >> 3) & 7);
  }

  for (int k0 = 0; k0 < K; k0 += 64) {
#pragma unroll
    for (int i = 0; i < 2; i++)
      gload_lds16(A + (i64)(m0 + rowA[i]) * K + k0 + (kgA[i] << 3),
                  (char*)As + (wave * 128 + i * 64) * 16);
#pragma unroll
    for (int i = 0; i < 4; i++)
      gload_lds16(W + (i64)rowW[i] * K + k0 + (kgW[i] << 3),
                  (char*)Ws + (wave * 256 + i * 64) * 16);
    __syncthreads();
#pragma unroll
    for (int kh = 0; kh < 2; kh++) {
      const int kb = (kh << 2) + (lane >> 4);
      bf16x8 af[4], bf[4];
#pragma unroll
      for (int m = 0; m < 4; m++) {
        const int row = (wr << 6) + (m << 4) + (lane & 15);
        af[m] = *(const bf16x8*)&As[row * 64 + ((kb ^ (row & 7)) << 3)];
      }
#pragma unroll
      for (int n = 0; n < 4; n++) {
        const int row = (wc << 6) + (n << 4) + (lane & 15);
        bf[n] = *(const bf16x8*)&Ws[row * 64 + ((kb ^ (row & 7)) << 3)];
      }
#pragma unroll
      for (int m = 0; m < 4; m++)
#pragma unroll
        for (int n = 0; n < 4; n++)
          acc[m][n] = __builtin_amdgcn_mfma_f32_16x16x32_bf16(bf[n], af[m], acc[m][n], 0, 0, 0);
    }
    __syncthreads();
  }

  // epilogue: v = R + acc + bias (f32), row-reduce for LN, normalize, store.
#pragma unroll
  for (int m = 0; m < 4; m++) {
    const int tokl = (wr << 6) + (m << 4) + (lane & 15);
    const i64 row = (i64)(m0 + tokl);
    float s = 0.f, q = 0.f;
#pragma unroll
    for (int n = 0; n < 4; n++) {
      const int col = (wc << 6) + (n << 4) + ((lane >> 4) << 2);
      const f32x4 bv = *(const f32x4*)&bias[col];
      const uint2 ru = *(const uint2*)&R[row * 256 + col];
      float v0 = acc[m][n][0] + bv[0] + b2f((ushort)(ru.x & 0xffff));
      float v1 = acc[m][n][1] + bv[1] + b2f((ushort)(ru.x >> 16));
      float v2 = acc[m][n][2] + bv[2] + b2f((ushort)(ru.y & 0xffff));
      float v3 = acc[m][n][3] + bv[3] + b2f((ushort)(ru.y >> 16));
      acc[m][n][0] = v0; acc[m][n][1] = v1; acc[m][n][2] = v2; acc[m][n][3] = v3;
      s += v0 + v1 + v2 + v3;
      q += v0 * v0 + v1 * v1 + v2 * v2 + v3 * v3;
    }
    s += __shfl_xor(s, 16, 64); s += __shfl_xor(s, 32, 64);
    q += __shfl_xor(q, 16, 64); q += __shfl_xor(q, 32, 64);
    if (lane < 16) { partS[tokl][wc] = s; partQ[tokl][wc] = q; }
  }
  __syncthreads();
#pragma unroll
  for (int m = 0; m < 4; m++) {
    const int tokl = (wr << 6) + (m << 4) + (lane & 15);
    const i64 row = (i64)(m0 + tokl);
    const f32x4 s4 = *(const f32x4*)&partS[tokl][0];
    const f32x4 q4 = *(const f32x4*)&partQ[tokl][0];
    const float mean = (s4[0] + s4[1] + s4[2] + s4[3]) * (1.f / 256.f);
    const float var = (q4[0] + q4[1] + q4[2] + q4[3]) * (1.f / 256.f) - mean * mean;
    const float rs = rsqrtf(var + 1e-5f);
#pragma unroll
    for (int n = 0; n < 4; n++) {
      const int col = (wc << 6) + (n << 4) + ((lane >> 4) << 2);
      const f32x4 g4 = *(const f32x4*)&g[col];
      const f32x4 b4 = *(const f32x4*)&b[col];
      uint2 o;
      o.x = pack2((acc[m][n][0] - mean) * rs * g4[0] + b4[0],
                  (acc[m][n][1] - mean) * rs * g4[1] + b4[1]);
      o.y = pack2((acc[m][n][2] - mean) * rs * g4[2] + b4[2],
                  (acc[m][n][3] - mean) * rs * g4[3] + b4[3]);
      *(uint2*)&C[row * 256 + col] = o;
    }
  }
}

// ---------------- Attention: per-seq, 4 heads = 4 waves, lane = query t -------
template <int S, bool ISV2E>
__global__ __launch_bounds__(256) void attn_k(const ushort* __restrict__ QKV,
                                              const int* __restrict__ mask,
                                              ushort* __restrict__ O, int seq0) {
  __shared__ float QL[4][S][68];
  __shared__ float KL[4][S][68];
  __shared__ float VL[4][S][68];
  const int h = threadIdx.x >> 6, lane = threadIdx.x & 63;
  const int seq = blockIdx.x;
  const i64 base = (i64)seq * S;
  const int gseq = seq0 + seq;

#pragma unroll
  for (int t = 0; t < S; t++) {
    const ushort* row = QKV + (base + t) * 768 + h * 64 + lane;
    QL[h][t][lane] = b2f(row[0]);
    KL[h][t][lane] = b2f(row[256]);
    VL[h][t][lane] = b2f(row[512]);
  }
  __syncthreads();

  if (lane < S) {
    const int t = lane;
    float q[64];
#pragma unroll
    for (int d4 = 0; d4 < 16; d4++) {
      float4 v = *(const float4*)&QL[h][t][d4 * 4];
      q[d4 * 4 + 0] = v.x; q[d4 * 4 + 1] = v.y;
      q[d4 * 4 + 2] = v.z; q[d4 * 4 + 3] = v.w;
    }
    float w[S];
    float mx = -1e30f;
#pragma unroll
    for (int s = 0; s < S; s++) {
      const bool valid = ISV2E ? (s == 0 || mask[(i64)gseq * ARITY + (s - 1)] != 0)
                               : (mask[(i64)gseq * S + s] != 0);
      float sc;
      if (valid) {
        sc = 0.f;
#pragma unroll
        for (int d4 = 0; d4 < 16; d4++) {
          float4 kv = *(const float4*)&KL[h][s][d4 * 4];
          sc = fmaf(q[d4 * 4 + 0], kv.x, sc);
          sc = fmaf(q[d4 * 4 + 1], kv.y, sc);
          sc = fmaf(q[d4 * 4 + 2], kv.z, sc);
          sc = fmaf(q[d4 * 4 + 3], kv.w, sc);
        }
        sc *= 0.125f;
      } else {
        sc = -1e9f;
      }
      w[s] = sc;
      mx = fmaxf(mx, sc);
    }
    float sum = 0.f;
#pragma unroll
    for (int s = 0; s < S; s++) { w[s] = __expf(w[s] - mx); sum += w[s]; }
    const float inv = 1.f / sum;
#pragma unroll
    for (int d4 = 0; d4 < 16; d4++) {
      float ox = 0.f, oy = 0.f, oz = 0.f, ow = 0.f;
#pragma unroll
      for (int s = 0; s < S; s++) {
        float4 vv = *(const float4*)&VL[h][s][d4 * 4];
        ox = fmaf(w[s], vv.x, ox); oy = fmaf(w[s], vv.y, oy);
        oz = fmaf(w[s], vv.z, oz); ow = fmaf(w[s], vv.w, ow);
      }
      float4 o; o.x = ox * inv; o.y = oy * inv; o.z = oz * inv; o.w = ow * inv;
      *(float4*)&QL[h][t][d4 * 4] = o;
    }
  }
  __syncthreads();
#pragma unroll
  for (int t = 0; t < S; t++)
    O[(base + t) * 256 + h * 64 + lane] = f2b(QL[h][t][lane]);
}

// ---------------- Gathers / scatters / conversion -----------------------------
__global__ __launch_bounds__(256) void f2b_cvt_k(const float* __restrict__ in,
                                                 ushort* __restrict__ out, int n) {
  for (int i = blockIdx.x * 256 + threadIdx.x; i < n; i += gridDim.x * 256)
    out[i] = f2b(in[i]);
}

__global__ __launch_bounds__(256) void gather_v2e_k(const float* __restrict__ unity,
                                                    const float* __restrict__ pos,
                                                    const int* __restrict__ xid,
                                                    const int* __restrict__ xpos,
                                                    ushort* __restrict__ X, int e0) {
  const int tk = blockIdx.x * 4 + (threadIdx.x >> 6);
  const int lane = threadIdx.x & 63;
  const int el = tk / SV, t = tk - el * SV;
  const int e = e0 + el;
  float4 v = make_float4(0.f, 0.f, 0.f, 0.f);
  if (t > 0) {
    const int id = xid[(i64)e * ARITY + (t - 1)];
    v = *(const float4*)&unity[(i64)id * 256 + lane * 4];
  }
  const int pp = xpos[(i64)e * SV + t];
  const float4 pv = *(const float4*)&pos[(i64)pp * 256 + lane * 4];
  uint2 o;
  o.x = pack2(v.x + pv.x, v.y + pv.y);
  o.y = pack2(v.z + pv.z, v.w + pv.w);
  *(uint2*)&X[(i64)tk * 256 + lane * 4] = o;
}

__global__ __launch_bounds__(256) void gather_e2v_k(const ushort* __restrict__ ext,
                                                    const int* __restrict__ hid,
                                                    ushort* __restrict__ X, int n0) {
  const int tk = blockIdx.x * 4 + (threadIdx.x >> 6);
  const int lane = threadIdx.x & 63;
  const int nl = tk / SE, j = tk - nl * SE;
  const int n = n0 + nl;
  const int id = hid[(i64)n * SE + j];
  *(uint2*)&X[(i64)tk * 256 + lane * 4] =
      *(const uint2*)&ext[(i64)id * 256 + lane * 4];
}

__global__ __launch_bounds__(256) void extract_he_k(const ushort* __restrict__ X,
                                                    ushort* __restrict__ ext, int e0) {
  const int el = blockIdx.x * 4 + (threadIdx.x >> 6);
  const int lane = threadIdx.x & 63;
  *(uint2*)&ext[(i64)(e0 + el) * 256 + lane * 4] =
      *(const uint2*)&X[(i64)el * SV * 256 + lane * 4];
}

__global__ __launch_bounds__(256) void scatter_k(const ushort* __restrict__ X,
                                                 const int* __restrict__ subg,
                                                 float* __restrict__ unity, int n0) {
  const int nl = blockIdx.x * 4 + (threadIdx.x >> 6);
  const int lane = threadIdx.x & 63;
  const int dst = subg[n0 + nl];
  ushort4 v = *(const ushort4*)&X[(i64)nl * SE * 256 + lane * 4];
  float4 o; o.x = b2f(v.x); o.y = b2f(v.y); o.z = b2f(v.z); o.w = b2f(v.w);
  *(float4*)&unity[(i64)dst * 256 + lane * 4] = o;
}

__global__ __launch_bounds__(256) void ext_init_k(ushort* __restrict__ ext,
                                                  const float* __restrict__ pad,
                                                  const float* __restrict__ cls) {
  const int d = threadIdx.x;
  ext[(i64)NHEDGE * 256 + d] = f2b(pad[d]);
  ext[(i64)(NHEDGE + 1) * 256 + d] = f2b(cls[d]);
}

__global__ __launch_bounds__(256) void out_gather_k(const ushort* __restrict__ ext,
                                                    const int* __restrict__ pred,
                                                    float* __restrict__ out) {
  const int i = blockIdx.x * 4 + (threadIdx.x >> 6);
  const int lane = threadIdx.x & 63;
  const int e = pred[i];
  ushort4 v = *(const ushort4*)&ext[(i64)e * 256 + lane * 4];
  float4 o; o.x = b2f(v.x); o.y = b2f(v.y); o.z = b2f(v.z); o.w = b2f(v.w);
  *(float4*)&out[(i64)i * 256 + lane * 4] = o;
}

// ---------------- Host orchestration ------------------------------------------
extern "C" void kernel_launch(void* const* d_in, const int* in_sizes, int n_in,
                              void* d_out, int out_size, void* d_ws, size_t ws_size,
                              hipStream_t stream) {
  (void)in_sizes; (void)n_in; (void)out_size;
  const float* unity_in = (const float*)d_in[0];
  const float* cls_emb  = (const float*)d_in[1];
  const float* pad_emb  = (const float*)d_in[2];
  const float* pos_tab  = (const float*)d_in[3];
  const float* qkv_w    = (const float*)d_in[4];
  const float* qkv_b    = (const float*)d_in[5];
  const float* out_w    = (const float*)d_in[6];
  const float* out_b    = (const float*)d_in[7];
  const float* ln1_g    = (const float*)d_in[8];
  const float* ln1_b    = (const float*)d_in[9];
  const float* ln2_g    = (const float*)d_in[10];
  const float* ln2_b    = (const float*)d_in[11];
  const float* ff1_w    = (const float*)d_in[12];
  const float* ff1_b    = (const float*)d_in[13];
  const float* ff2_w    = (const float*)d_in[14];
  const float* ff2_b    = (const float*)d_in[15];
  const int* xid   = (const int*)d_in[16];
  const int* vmask = (const int*)d_in[17];
  const int* xpos  = (const int*)d_in[18];
  const int* hid   = (const int*)d_in[19];
  const int* hmask = (const int*)d_in[20];
  const int* subg  = (const int*)d_in[21];
  const int* pred  = (const int*)d_in[22];

  // ---- workspace layout (adaptive CHUNK) ----
  const i64 unity_b = (i64)NTOTAL * 256 * 4;          // fp32, 102.4 MB
  const i64 ext_b   = (i64)(NHEDGE + 2) * 256 * 2;    // bf16, 16.8 MB
  const int nq = 2 * 768 * 256, no = 2 * 256 * 256,
            n1 = 2 * 1024 * 256, n2 = 2 * 256 * 1024;
  const i64 wts_b = (i64)(nq + no + n1 + n2) * 2;     // 3.1 MB
  const i64 per_elem = (i64)SE * (512 + 2048 + 512);  // X+Y+O bytes
  int CHUNK = 8192;
  while (CHUNK > 128 && unity_b + ext_b + wts_b + (i64)CHUNK * per_elem > (i64)ws_size)
    CHUNK >>= 1;

  char* w = (char*)d_ws;
  float*  unity = (float*)w;  w += unity_b;
  ushort* ext   = (ushort*)w; w += ext_b;
  ushort* wq    = (ushort*)w; w += (i64)nq * 2;
  ushort* wo    = (ushort*)w; w += (i64)no * 2;
  ushort* w1    = (ushort*)w; w += (i64)n1 * 2;
  ushort* w2    = (ushort*)w; w += (i64)n2 * 2;
  ushort* X     = (ushort*)w; w += (i64)CHUNK * SE * 256 * 2;
  ushort* Y     = (ushort*)w; w += (i64)CHUNK * SE * 1024 * 2;
  ushort* O     = (ushort*)w; w += (i64)CHUNK * SE * 256 * 2;

  f2b_cvt_k<<<512, 256, 0, stream>>>(qkv_w, wq, nq);
  f2b_cvt_k<<<512, 256, 0, stream>>>(out_w, wo, no);
  f2b_cvt_k<<<512, 256, 0, stream>>>(ff1_w, w1, n1);
  f2b_cvt_k<<<512, 256, 0, stream>>>(ff2_w, w2, n2);
  hipMemcpyAsync(unity, unity_in, unity_b, hipMemcpyDeviceToDevice, stream);
  ext_init_k<<<1, 256, 0, stream>>>(ext, pad_emb, cls_emb);

  for (int k = 0; k <= 2; k++) {
    // ---- V2E ----
    for (int c = 0; c < NHEDGE / CHUNK; c++) {
      const int e0 = c * CHUNK;
      const int M = CHUNK * SV;
      gather_v2e_k<<<M / 4, 256, 0, stream>>>(unity, pos_tab, xid, xpos, X, e0);
      for (int l = 0; l < 2; l++) {
        gemm_bf16_k<256, 1><<<dim3(6, M / 128), 256, 0, stream>>>(
            X, wq + (i64)l * 768 * 256, qkv_b + l * 768, Y, M, 768);
        attn_k<SV, true><<<CHUNK, 256, 0, stream>>>(Y, vmask, O, e0);
        gemm_ln_k<256><<<M / 128, 512, 0, stream>>>(
            O, wo + (i64)l * 256 * 256, out_b + l * 256, X,
            ln1_g + l * 256, ln1_b + l * 256, X, M);
        gemm_bf16_k<256, 2><<<dim3(8, M / 128), 256, 0, stream>>>(
            X, w1 + (i64)l * 1024 * 256, ff1_b + l * 1024, Y, M, 1024);
        gemm_ln_k<1024><<<M / 128, 512, 0, stream>>>(
            Y, w2 + (i64)l * 256 * 1024, ff2_b + l * 256, X,
            ln2_g + l * 256, ln2_b + l * 256, X, M);
      }
      extract_he_k<<<CHUNK / 4, 256, 0, stream>>>(X, ext, e0);
    }
    // ---- E2V ----
    if (k < 2) {
      for (int c = 0; c < NNODE / CHUNK; c++) {
        const int n0 = c * CHUNK;
        const int M = CHUNK * SE;
        gather_e2v_k<<<M / 4, 256, 0, stream>>>(ext, hid, X, n0);
        for (int l = 0; l < 2; l++) {
          gemm_bf16_k<256, 1><<<dim3(6, M / 128), 256, 0, stream>>>(
              X, wq + (i64)l * 768 * 256, qkv_b + l * 768, Y, M, 768);
          attn_k<SE, false><<<CHUNK, 256, 0, stream>>>(Y, hmask, O, n0);
          gemm_ln_k<256><<<M / 128, 512, 0, stream>>>(
              O, wo + (i64)l * 256 * 256, out_b + l * 256, X,
              ln1_g + l * 256, ln1_b + l * 256, X, M);
          gemm_bf16_k<256, 2><<<dim3(8, M / 128), 256, 0, stream>>>(
              X, w1 + (i64)l * 1024 * 256, ff1_b + l * 1024, Y, M, 1024);
          gemm_ln_k<1024><<<M / 128, 512, 0, stream>>>(
              Y, w2 + (i64)l * 256 * 1024, ff2_b + l * 256, X,
              ln2_g + l * 256, ln2_b + l * 256, X, M);
        }
        scatter_k<<<CHUNK / 4, 256, 0, stream>>>(X, subg, unity, n0);
      }
    }
  }
  out_gather_k<<<64, 256, 0, stream>>>(ext, pred, (float*)d_out);
}

// Round 5
// 33403.571 us; speedup vs baseline: 4.6529x; 1.0022x over previous
//
#include <hip/hip_runtime.h>
#include <stdint.h>

typedef long long i64;
typedef __attribute__((ext_vector_type(8))) short bf16x8;
typedef __attribute__((ext_vector_type(4))) float f32x4;

#define SV 11
#define SE 17
#define ARITY 10
#define NHEDGE 32768
#define NNODE 65536
#define NTOTAL 100000

__device__ __forceinline__ float wredsum(float s) {
#pragma unroll
  for (int o = 32; o > 0; o >>= 1) s += __shfl_xor(s, o, 64);
  return s;
}

__device__ __forceinline__ float b2f(ushort u) {
  union { uint32_t i; float f; } v; v.i = (uint32_t)u << 16; return v.f;
}
__device__ __forceinline__ ushort f2b(float f) {
  union { float f; uint32_t i; } v; v.f = f;
  uint32_t u = v.i + 0x7fffu + ((v.i >> 16) & 1u);
  return (ushort)(u >> 16);
}
__device__ __forceinline__ uint pack2(float a, float b) {
  return (uint)f2b(a) | ((uint)f2b(b) << 16);
}

__device__ __forceinline__ void gload_lds16(const void* g, void* l) {
  __builtin_amdgcn_global_load_lds((const __attribute__((address_space(1))) void*)g,
                                   (__attribute__((address_space(3))) void*)l, 16, 0, 0);
}

// bijective XCD swizzle (m204): consecutive remapped ids stay on one XCD so
// col-blocks sharing an A-panel hit the same L2.
__device__ __forceinline__ int xcd_swizzle(int orig, int nwg) {
  const int xcd = orig & 7, rest = orig >> 3;
  const int q = nwg >> 3, r = nwg & 7;
  return (xcd < r ? xcd * (q + 1) : r * (q + 1) + (xcd - r) * q) + rest;
}

// -------- bf16 MFMA GEMM: C[M,N] = act(A[M,K] @ W[N,K]^T + bias) --------------
// MODE: 0 = none, 1 = +bias, 2 = +bias+relu.  Tile 128x128, BK=64, 4 waves.
// Swapped-operand MFMA -> 4 consecutive output cols per lane -> 8B stores.
// Pipelined: stage(t+1) issued after the read-barrier, flies under MFMA(t).
template <int K, int MODE>
__global__ __launch_bounds__(256) void gemm_bf16_k(const ushort* __restrict__ A,
                                                   const ushort* __restrict__ W,
                                                   const float* __restrict__ bias,
                                                   ushort* __restrict__ C, int M, int N) {
  __shared__ ushort As[128 * 64];
  __shared__ ushort Ws[128 * 64];
  const int tid = threadIdx.x;
  const int wave = tid >> 6, lane = tid & 63;
  const int nwg = gridDim.x * gridDim.y;
  const int wg = xcd_swizzle(blockIdx.y * gridDim.x + blockIdx.x, nwg);
  const int bx = wg % gridDim.x, by = wg / gridDim.x;
  const int m0 = by << 7, n0 = bx << 7;
  const int wr = wave >> 1, wc = wave & 1;

  f32x4 acc[4][4];
#pragma unroll
  for (int m = 0; m < 4; m++)
#pragma unroll
    for (int n = 0; n < 4; n++) acc[m][n] = (f32x4){0.f, 0.f, 0.f, 0.f};

  const int srow = (wave << 5) + (lane >> 3);
  const int kblk_g = (lane & 7) ^ (lane >> 3);
  const ushort* Ag = A + (i64)(m0 + srow) * K + (kblk_g << 3);
  const ushort* Wg = W + (i64)(n0 + srow) * K + (kblk_g << 3);
  char* lA = (char*)As + (wave << 12);
  char* lB = (char*)Ws + (wave << 12);

  // prologue: stage k0 = 0
#pragma unroll
  for (int i = 0; i < 4; i++) {
    gload_lds16(Ag + (i64)(i * 8) * K, lA + i * 1024);
    gload_lds16(Wg + (i64)(i * 8) * K, lB + i * 1024);
  }

  for (int k0 = 0; k0 < K; k0 += 64) {
    __syncthreads();  // own vmcnt drained by barrier -> staged data visible
    bf16x8 af[2][4], bf[2][4];
#pragma unroll
    for (int kh = 0; kh < 2; kh++) {
      const int kb = (kh << 2) + (lane >> 4);
#pragma unroll
      for (int m = 0; m < 4; m++) {
        const int row = (wr << 6) + (m << 4) + (lane & 15);
        af[kh][m] = *(const bf16x8*)&As[row * 64 + ((kb ^ (row & 7)) << 3)];
      }
#pragma unroll
      for (int n = 0; n < 4; n++) {
        const int row = (wc << 6) + (n << 4) + (lane & 15);
        bf[kh][n] = *(const bf16x8*)&Ws[row * 64 + ((kb ^ (row & 7)) << 3)];
      }
    }
    __syncthreads();  // all waves done reading -> safe to overwrite
    if (k0 + 64 < K) {
#pragma unroll
      for (int i = 0; i < 4; i++) {
        gload_lds16(Ag + (k0 + 64) + (i64)(i * 8) * K, lA + i * 1024);
        gload_lds16(Wg + (k0 + 64) + (i64)(i * 8) * K, lB + i * 1024);
      }
    }
#pragma unroll
    for (int kh = 0; kh < 2; kh++)
#pragma unroll
      for (int m = 0; m < 4; m++)
#pragma unroll
        for (int n = 0; n < 4; n++)
          acc[m][n] = __builtin_amdgcn_mfma_f32_16x16x32_bf16(bf[kh][n], af[kh][m], acc[m][n], 0, 0, 0);
  }

#pragma unroll
  for (int m = 0; m < 4; m++) {
    const int row = m0 + (wr << 6) + (m << 4) + (lane & 15);
#pragma unroll
    for (int n = 0; n < 4; n++) {
      const int col = n0 + (wc << 6) + (n << 4) + ((lane >> 4) << 2);
      float v0 = acc[m][n][0], v1 = acc[m][n][1], v2 = acc[m][n][2], v3 = acc[m][n][3];
      if (MODE > 0) {
        const f32x4 bv = *(const f32x4*)&bias[col];
        v0 += bv[0]; v1 += bv[1]; v2 += bv[2]; v3 += bv[3];
      }
      if (MODE == 2) {
        v0 = fmaxf(v0, 0.f); v1 = fmaxf(v1, 0.f);
        v2 = fmaxf(v2, 0.f); v3 = fmaxf(v3, 0.f);
      }
      uint2 o; o.x = pack2(v0, v1); o.y = pack2(v2, v3);
      *(uint2*)&C[(i64)row * N + col] = o;
    }
  }
}

// -------- Fused GEMM + residual + LayerNorm (N = 256 fixed) -------------------
// C/X = LN(R + A@W^T + bias) * g + b.   Tile 128x256, 8 waves (2r x 4c).
template <int K>
__global__ __launch_bounds__(512) void gemm_ln_k(const ushort* __restrict__ A,
                                                 const ushort* __restrict__ W,
                                                 const float* __restrict__ bias,
                                                 const ushort* R,
                                                 const float* __restrict__ g,
                                                 const float* __restrict__ b,
                                                 ushort* C, int M) {
  __shared__ ushort As[128 * 64];
  __shared__ ushort Ws[256 * 64];
  __shared__ float partS[128][4];
  __shared__ float partQ[128][4];
  const int tid = threadIdx.x;
  const int wave = tid >> 6, lane = tid & 63;
  const int m0 = blockIdx.x << 7;
  const int wr = wave >> 2, wc = wave & 3;

  f32x4 acc[4][4];
#pragma unroll
  for (int m = 0; m < 4; m++)
#pragma unroll
    for (int n = 0; n < 4; n++) acc[m][n] = (f32x4){0.f, 0.f, 0.f, 0.f};

  int rowA[2], kgA[2];
#pragma unroll
  for (int i = 0; i < 2; i++) {
    const int u = wave * 128 + i * 64 + lane;
    rowA[i] = u >> 3; kgA[i] = (u & 7) ^ ((u >> 3) & 7);
  }
  int rowW[4], kgW[4];
#pragma unroll
  for (int i = 0; i < 4; i++) {
    const int u = wave * 256 + i * 64 + lane;
    rowW[i] = u >> 3; kgW[i] = (u & 7) ^ ((u >> 3) & 7);
  }

  // prologue stage k0 = 0
#pragma unroll
  for (int i = 0; i < 2; i++)
    gload_lds16(A + (i64)(m0 + rowA[i]) * K + (kgA[i] << 3),
                (char*)As + (wave * 128 + i * 64) * 16);
#pragma unroll
  for (int i = 0; i < 4; i++)
    gload_lds16(W + (i64)rowW[i] * K + (kgW[i] << 3),
                (char*)Ws + (wave * 256 + i * 64) * 16);

  for (int k0 = 0; k0 < K; k0 += 64) {
    __syncthreads();
    bf16x8 af[2][4], bf[2][4];
#pragma unroll
    for (int kh = 0; kh < 2; kh++) {
      const int kb = (kh << 2) + (lane >> 4);
#pragma unroll
      for (int m = 0; m < 4; m++) {
        const int row = (wr << 6) + (m << 4) + (lane & 15);
        af[kh][m] = *(const bf16x8*)&As[row * 64 + ((kb ^ (row & 7)) << 3)];
      }
#pragma unroll
      for (int n = 0; n < 4; n++) {
        const int row = (wc << 6) + (n << 4) + (lane & 15);
        bf[kh][n] = *(const bf16x8*)&Ws[row * 64 + ((kb ^ (row & 7)) << 3)];
      }
    }
    __syncthreads();
    if (k0 + 64 < K) {
#pragma unroll
      for (int i = 0; i < 2; i++)
        gload_lds16(A + (i64)(m0 + rowA[i]) * K + (k0 + 64) + (kgA[i] << 3),
                    (char*)As + (wave * 128 + i * 64) * 16);
#pragma unroll
      for (int i = 0; i < 4; i++)
        gload_lds16(W + (i64)rowW[i] * K + (k0 + 64) + (kgW[i] << 3),
                    (char*)Ws + (wave * 256 + i * 64) * 16);
    }
#pragma unroll
    for (int kh = 0; kh < 2; kh++)
#pragma unroll
      for (int m = 0; m < 4; m++)
#pragma unroll
        for (int n = 0; n < 4; n++)
          acc[m][n] = __builtin_amdgcn_mfma_f32_16x16x32_bf16(bf[kh][n], af[kh][m], acc[m][n], 0, 0, 0);
  }

  // epilogue: v = R + acc + bias (f32), row-reduce for LN, normalize, store.
#pragma unroll
  for (int m = 0; m < 4; m++) {
    const int tokl = (wr << 6) + (m << 4) + (lane & 15);
    const i64 row = (i64)(m0 + tokl);
    float s = 0.f, q = 0.f;
#pragma unroll
    for (int n = 0; n < 4; n++) {
      const int col = (wc << 6) + (n << 4) + ((lane >> 4) << 2);
      const f32x4 bv = *(const f32x4*)&bias[col];
      const uint2 ru = *(const uint2*)&R[row * 256 + col];
      float v0 = acc[m][n][0] + bv[0] + b2f((ushort)(ru.x & 0xffff));
      float v1 = acc[m][n][1] + bv[1] + b2f((ushort)(ru.x >> 16));
      float v2 = acc[m][n][2] + bv[2] + b2f((ushort)(ru.y & 0xffff));
      float v3 = acc[m][n][3] + bv[3] + b2f((ushort)(ru.y >> 16));
      acc[m][n][0] = v0; acc[m][n][1] = v1; acc[m][n][2] = v2; acc[m][n][3] = v3;
      s += v0 + v1 + v2 + v3;
      q += v0 * v0 + v1 * v1 + v2 * v2 + v3 * v3;
    }
    s += __shfl_xor(s, 16, 64); s += __shfl_xor(s, 32, 64);
    q += __shfl_xor(q, 16, 64); q += __shfl_xor(q, 32, 64);
    if (lane < 16) { partS[tokl][wc] = s; partQ[tokl][wc] = q; }
  }
  __syncthreads();
#pragma unroll
  for (int m = 0; m < 4; m++) {
    const int tokl = (wr << 6) + (m << 4) + (lane & 15);
    const i64 row = (i64)(m0 + tokl);
    const f32x4 s4 = *(const f32x4*)&partS[tokl][0];
    const f32x4 q4 = *(const f32x4*)&partQ[tokl][0];
    const float mean = (s4[0] + s4[1] + s4[2] + s4[3]) * (1.f / 256.f);
    const float var = (q4[0] + q4[1] + q4[2] + q4[3]) * (1.f / 256.f) - mean * mean;
    const float rs = rsqrtf(var + 1e-5f);
#pragma unroll
    for (int n = 0; n < 4; n++) {
      const int col = (wc << 6) + (n << 4) + ((lane >> 4) << 2);
      const f32x4 g4 = *(const f32x4*)&g[col];
      const f32x4 b4 = *(const f32x4*)&b[col];
      uint2 o;
      o.x = pack2((acc[m][n][0] - mean) * rs * g4[0] + b4[0],
                  (acc[m][n][1] - mean) * rs * g4[1] + b4[1]);
      o.y = pack2((acc[m][n][2] - mean) * rs * g4[2] + b4[2],
                  (acc[m][n][3] - mean) * rs * g4[3] + b4[3]);
      *(uint2*)&C[row * 256 + col] = o;
    }
  }
}

// ---------------- Attention: per-seq, 4 heads = 4 waves, lane = query t -------
template <int S, bool ISV2E>
__global__ __launch_bounds__(256) void attn_k(const ushort* __restrict__ QKV,
                                              const int* __restrict__ mask,
                                              ushort* __restrict__ O, int seq0) {
  __shared__ float QL[4][S][68];
  __shared__ float KL[4][S][68];
  __shared__ float VL[4][S][68];
  const int h = threadIdx.x >> 6, lane = threadIdx.x & 63;
  const int seq = blockIdx.x;
  const i64 base = (i64)seq * S;
  const int gseq = seq0 + seq;

#pragma unroll
  for (int t = 0; t < S; t++) {
    const ushort* row = QKV + (base + t) * 768 + h * 64 + lane;
    QL[h][t][lane] = b2f(row[0]);
    KL[h][t][lane] = b2f(row[256]);
    VL[h][t][lane] = b2f(row[512]);
  }
  __syncthreads();

  if (lane < S) {
    const int t = lane;
    float q[64];
#pragma unroll
    for (int d4 = 0; d4 < 16; d4++) {
      float4 v = *(const float4*)&QL[h][t][d4 * 4];
      q[d4 * 4 + 0] = v.x; q[d4 * 4 + 1] = v.y;
      q[d4 * 4 + 2] = v.z; q[d4 * 4 + 3] = v.w;
    }
    float w[S];
    float mx = -1e30f;
#pragma unroll
    for (int s = 0; s < S; s++) {
      const bool valid = ISV2E ? (s == 0 || mask[(i64)gseq * ARITY + (s - 1)] != 0)
                               : (mask[(i64)gseq * S + s] != 0);
      float sc;
      if (valid) {
        sc = 0.f;
#pragma unroll
        for (int d4 = 0; d4 < 16; d4++) {
          float4 kv = *(const float4*)&KL[h][s][d4 * 4];
          sc = fmaf(q[d4 * 4 + 0], kv.x, sc);
          sc = fmaf(q[d4 * 4 + 1], kv.y, sc);
          sc = fmaf(q[d4 * 4 + 2], kv.z, sc);
          sc = fmaf(q[d4 * 4 + 3], kv.w, sc);
        }
        sc *= 0.125f;
      } else {
        sc = -1e9f;
      }
      w[s] = sc;
      mx = fmaxf(mx, sc);
    }
    float sum = 0.f;
#pragma unroll
    for (int s = 0; s < S; s++) { w[s] = __expf(w[s] - mx); sum += w[s]; }
    const float inv = 1.f / sum;
#pragma unroll
    for (int d4 = 0; d4 < 16; d4++) {
      float ox = 0.f, oy = 0.f, oz = 0.f, ow = 0.f;
#pragma unroll
      for (int s = 0; s < S; s++) {
        float4 vv = *(const float4*)&VL[h][s][d4 * 4];
        ox = fmaf(w[s], vv.x, ox); oy = fmaf(w[s], vv.y, oy);
        oz = fmaf(w[s], vv.z, oz); ow = fmaf(w[s], vv.w, ow);
      }
      float4 o; o.x = ox * inv; o.y = oy * inv; o.z = oz * inv; o.w = ow * inv;
      *(float4*)&QL[h][t][d4 * 4] = o;
    }
  }
  __syncthreads();
#pragma unroll
  for (int t = 0; t < S; t++)
    O[(base + t) * 256 + h * 64 + lane] = f2b(QL[h][t][lane]);
}

// ---------------- Gathers / scatters / conversion -----------------------------
__global__ __launch_bounds__(256) void f2b_cvt_k(const float* __restrict__ in,
                                                 ushort* __restrict__ out, int n) {
  for (int i = blockIdx.x * 256 + threadIdx.x; i < n; i += gridDim.x * 256)
    out[i] = f2b(in[i]);
}

__global__ __launch_bounds__(256) void gather_v2e_k(const float* __restrict__ unity,
                                                    const float* __restrict__ pos,
                                                    const int* __restrict__ xid,
                                                    const int* __restrict__ xpos,
                                                    ushort* __restrict__ X, int e0) {
  const int tk = blockIdx.x * 4 + (threadIdx.x >> 6);
  const int lane = threadIdx.x & 63;
  const int el = tk / SV, t = tk - el * SV;
  const int e = e0 + el;
  float4 v = make_float4(0.f, 0.f, 0.f, 0.f);
  if (t > 0) {
    const int id = xid[(i64)e * ARITY + (t - 1)];
    v = *(const float4*)&unity[(i64)id * 256 + lane * 4];
  }
  const int pp = xpos[(i64)e * SV + t];
  const float4 pv = *(const float4*)&pos[(i64)pp * 256 + lane * 4];
  uint2 o;
  o.x = pack2(v.x + pv.x, v.y + pv.y);
  o.y = pack2(v.z + pv.z, v.w + pv.w);
  *(uint2*)&X[(i64)tk * 256 + lane * 4] = o;
}

__global__ __launch_bounds__(256) void gather_e2v_k(const ushort* __restrict__ ext,
                                                    const int* __restrict__ hid,
                                                    ushort* __restrict__ X, int n0) {
  const int tk = blockIdx.x * 4 + (threadIdx.x >> 6);
  const int lane = threadIdx.x & 63;
  const int nl = tk / SE, j = tk - nl * SE;
  const int n = n0 + nl;
  const int id = hid[(i64)n * SE + j];
  *(uint2*)&X[(i64)tk * 256 + lane * 4] =
      *(const uint2*)&ext[(i64)id * 256 + lane * 4];
}

__global__ __launch_bounds__(256) void extract_he_k(const ushort* __restrict__ X,
                                                    ushort* __restrict__ ext, int e0) {
  const int el = blockIdx.x * 4 + (threadIdx.x >> 6);
  const int lane = threadIdx.x & 63;
  *(uint2*)&ext[(i64)(e0 + el) * 256 + lane * 4] =
      *(const uint2*)&X[(i64)el * SV * 256 + lane * 4];
}

__global__ __launch_bounds__(256) void scatter_k(const ushort* __restrict__ X,
                                                 const int* __restrict__ subg,
                                                 float* __restrict__ unity, int n0) {
  const int nl = blockIdx.x * 4 + (threadIdx.x >> 6);
  const int lane = threadIdx.x & 63;
  const int dst = subg[n0 + nl];
  ushort4 v = *(const ushort4*)&X[(i64)nl * SE * 256 + lane * 4];
  float4 o; o.x = b2f(v.x); o.y = b2f(v.y); o.z = b2f(v.z); o.w = b2f(v.w);
  *(float4*)&unity[(i64)dst * 256 + lane * 4] = o;
}

__global__ __launch_bounds__(256) void ext_init_k(ushort* __restrict__ ext,
                                                  const float* __restrict__ pad,
                                                  const float* __restrict__ cls) {
  const int d = threadIdx.x;
  ext[(i64)NHEDGE * 256 + d] = f2b(pad[d]);
  ext[(i64)(NHEDGE + 1) * 256 + d] = f2b(cls[d]);
}

__global__ __launch_bounds__(256) void out_gather_k(const ushort* __restrict__ ext,
                                                    const int* __restrict__ pred,
                                                    float* __restrict__ out) {
  const int i = blockIdx.x * 4 + (threadIdx.x >> 6);
  const int lane = threadIdx.x & 63;
  const int e = pred[i];
  ushort4 v = *(const ushort4*)&ext[(i64)e * 256 + lane * 4];
  float4 o; o.x = b2f(v.x); o.y = b2f(v.y); o.z = b2f(v.z); o.w = b2f(v.w);
  *(float4*)&out[(i64)i * 256 + lane * 4] = o;
}

// ---------------- Host orchestration ------------------------------------------
extern "C" void kernel_launch(void* const* d_in, const int* in_sizes, int n_in,
                              void* d_out, int out_size, void* d_ws, size_t ws_size,
                              hipStream_t stream) {
  (void)in_sizes; (void)n_in; (void)out_size;
  const float* unity_in = (const float*)d_in[0];
  const float* cls_emb  = (const float*)d_in[1];
  const float* pad_emb  = (const float*)d_in[2];
  const float* pos_tab  = (const float*)d_in[3];
  const float* qkv_w    = (const float*)d_in[4];
  const float* qkv_b    = (const float*)d_in[5];
  const float* out_w    = (const float*)d_in[6];
  const float* out_b    = (const float*)d_in[7];
  const float* ln1_g    = (const float*)d_in[8];
  const float* ln1_b    = (const float*)d_in[9];
  const float* ln2_g    = (const float*)d_in[10];
  const float* ln2_b    = (const float*)d_in[11];
  const float* ff1_w    = (const float*)d_in[12];
  const float* ff1_b    = (const float*)d_in[13];
  const float* ff2_w    = (const float*)d_in[14];
  const float* ff2_b    = (const float*)d_in[15];
  const int* xid   = (const int*)d_in[16];
  const int* vmask = (const int*)d_in[17];
  const int* xpos  = (const int*)d_in[18];
  const int* hid   = (const int*)d_in[19];
  const int* hmask = (const int*)d_in[20];
  const int* subg  = (const int*)d_in[21];
  const int* pred  = (const int*)d_in[22];

  // ---- workspace layout (adaptive CHUNK) ----
  const i64 unity_b = (i64)NTOTAL * 256 * 4;          // fp32, 102.4 MB
  const i64 ext_b   = (i64)(NHEDGE + 2) * 256 * 2;    // bf16, 16.8 MB
  const int nq = 2 * 768 * 256, no = 2 * 256 * 256,
            n1 = 2 * 1024 * 256, n2 = 2 * 256 * 1024;
  const i64 wts_b = (i64)(nq + no + n1 + n2) * 2;     // 3.1 MB
  const i64 per_elem = (i64)SE * (512 + 2048 + 512);  // X+Y+O bytes
  int CHUNK = 8192;
  while (CHUNK > 128 && unity_b + ext_b + wts_b + (i64)CHUNK * per_elem > (i64)ws_size)
    CHUNK >>= 1;

  char* w = (char*)d_ws;
  float*  unity = (float*)w;  w += unity_b;
  ushort* ext   = (ushort*)w; w += ext_b;
  ushort* wq    = (ushort*)w; w += (i64)nq * 2;
  ushort* wo    = (ushort*)w; w += (i64)no * 2;
  ushort* w1    = (ushort*)w; w += (i64)n1 * 2;
  ushort* w2    = (ushort*)w; w += (i64)n2 * 2;
  ushort* X     = (ushort*)w; w += (i64)CHUNK * SE * 256 * 2;
  ushort* Y     = (ushort*)w; w += (i64)CHUNK * SE * 1024 * 2;
  ushort* O     = (ushort*)w; w += (i64)CHUNK * SE * 256 * 2;

  f2b_cvt_k<<<512, 256, 0, stream>>>(qkv_w, wq, nq);
  f2b_cvt_k<<<512, 256, 0, stream>>>(out_w, wo, no);
  f2b_cvt_k<<<512, 256, 0, stream>>>(ff1_w, w1, n1);
  f2b_cvt_k<<<512, 256, 0, stream>>>(ff2_w, w2, n2);
  hipMemcpyAsync(unity, unity_in, unity_b, hipMemcpyDeviceToDevice, stream);
  ext_init_k<<<1, 256, 0, stream>>>(ext, pad_emb, cls_emb);

  for (int k = 0; k <= 2; k++) {
    // ---- V2E ----
    for (int c = 0; c < NHEDGE / CHUNK; c++) {
      const int e0 = c * CHUNK;
      const int M = CHUNK * SV;
      gather_v2e_k<<<M / 4, 256, 0, stream>>>(unity, pos_tab, xid, xpos, X, e0);
      for (int l = 0; l < 2; l++) {
        gemm_bf16_k<256, 1><<<dim3(6, M / 128), 256, 0, stream>>>(
            X, wq + (i64)l * 768 * 256, qkv_b + l * 768, Y, M, 768);
        attn_k<SV, true><<<CHUNK, 256, 0, stream>>>(Y, vmask, O, e0);
        gemm_ln_k<256><<<M / 128, 512, 0, stream>>>(
            O, wo + (i64)l * 256 * 256, out_b + l * 256, X,
            ln1_g + l * 256, ln1_b + l * 256, X, M);
        gemm_bf16_k<256, 2><<<dim3(8, M / 128), 256, 0, stream>>>(
            X, w1 + (i64)l * 1024 * 256, ff1_b + l * 1024, Y, M, 1024);
        gemm_ln_k<1024><<<M / 128, 512, 0, stream>>>(
            Y, w2 + (i64)l * 256 * 1024, ff2_b + l * 256, X,
            ln2_g + l * 256, ln2_b + l * 256, X, M);
      }
      extract_he_k<<<CHUNK / 4, 256, 0, stream>>>(X, ext, e0);
    }
    // ---- E2V ----
    if (k < 2) {
      for (int c = 0; c < NNODE / CHUNK; c++) {
        const int n0 = c * CHUNK;
        const int M = CHUNK * SE;
        gather_e2v_k<<<M / 4, 256, 0, stream>>>(ext, hid, X, n0);
        for (int l = 0; l < 2; l++) {
          gemm_bf16_k<256, 1><<<dim3(6, M / 128), 256, 0, stream>>>(
              X, wq + (i64)l * 768 * 256, qkv_b + l * 768, Y, M, 768);
          attn_k<SE, false><<<CHUNK, 256, 0, stream>>>(Y, hmask, O, n0);
          gemm_ln_k<256><<<M / 128, 512, 0, stream>>>(
              O, wo + (i64)l * 256 * 256, out_b + l * 256, X,
              ln1_g + l * 256, ln1_b + l * 256, X, M);
          gemm_bf16_k<256, 2><<<dim3(8, M / 128), 256, 0, stream>>>(
              X, w1 + (i64)l * 1024 * 256, ff1_b + l * 1024, Y, M, 1024);
          gemm_ln_k<1024><<<M / 128, 512, 0, stream>>>(
              Y, w2 + (i64)l * 256 * 1024, ff2_b + l * 256, X,
              ln2_g + l * 256, ln2_b + l * 256, X, M);
        }
        scatter_k<<<CHUNK / 4, 256, 0, stream>>>(X, subg, unity, n0);
      }
    }
  }
  out_gather_k<<<64, 256, 0, stream>>>(ext, pred, (float*)d_out);
}

// Round 6
// 22326.314 us; speedup vs baseline: 6.9615x; 1.4962x over previous
//
#include <hip/hip_runtime.h>
#include <stdint.h>

typedef long long i64;
typedef __attribute__((ext_vector_type(8))) short bf16x8;
typedef __attribute__((ext_vector_type(4))) float f32x4;

#define SV 11
#define SE 17
#define ARITY 10
#define NHEDGE 32768
#define NNODE 65536
#define NTOTAL 100000

__device__ __forceinline__ float b2f(ushort u) {
  union { uint32_t i; float f; } v; v.i = (uint32_t)u << 16; return v.f;
}
__device__ __forceinline__ ushort f2b(float f) {
  union { float f; uint32_t i; } v; v.f = f;
  uint32_t u = v.i + 0x7fffu + ((v.i >> 16) & 1u);
  return (ushort)(u >> 16);
}
__device__ __forceinline__ uint pack2(float a, float b) {
  return (uint)f2b(a) | ((uint)f2b(b) << 16);
}
__device__ __forceinline__ void cvt8(uint4 v, float* f) {
  f[0] = b2f((ushort)(v.x & 0xffff)); f[1] = b2f((ushort)(v.x >> 16));
  f[2] = b2f((ushort)(v.y & 0xffff)); f[3] = b2f((ushort)(v.y >> 16));
  f[4] = b2f((ushort)(v.z & 0xffff)); f[5] = b2f((ushort)(v.z >> 16));
  f[6] = b2f((ushort)(v.w & 0xffff)); f[7] = b2f((ushort)(v.w >> 16));
}

__device__ __forceinline__ void gload_lds16(const void* g, void* l) {
  __builtin_amdgcn_global_load_lds((const __attribute__((address_space(1))) void*)g,
                                   (__attribute__((address_space(3))) void*)l, 16, 0, 0);
}

__device__ __forceinline__ int xcd_swizzle(int orig, int nwg) {
  const int xcd = orig & 7, rest = orig >> 3;
  const int q = nwg >> 3, r = nwg & 7;
  return (xcd < r ? xcd * (q + 1) : r * (q + 1) + (xcd - r) * q) + rest;
}

// -------- bf16 MFMA GEMM: C[M,N] = act(A[M,K] @ W[N,K]^T + bias) --------------
template <int K, int MODE>
__global__ __launch_bounds__(256) void gemm_bf16_k(const ushort* __restrict__ A,
                                                   const ushort* __restrict__ W,
                                                   const float* __restrict__ bias,
                                                   ushort* __restrict__ C, int M, int N) {
  __shared__ ushort As[128 * 64];
  __shared__ ushort Ws[128 * 64];
  const int tid = threadIdx.x;
  const int wave = tid >> 6, lane = tid & 63;
  const int nwg = gridDim.x * gridDim.y;
  const int wg = xcd_swizzle(blockIdx.y * gridDim.x + blockIdx.x, nwg);
  const int bx = wg % gridDim.x, by = wg / gridDim.x;
  const int m0 = by << 7, n0 = bx << 7;
  const int wr = wave >> 1, wc = wave & 1;

  f32x4 acc[4][4];
#pragma unroll
  for (int m = 0; m < 4; m++)
#pragma unroll
    for (int n = 0; n < 4; n++) acc[m][n] = (f32x4){0.f, 0.f, 0.f, 0.f};

  const int srow = (wave << 5) + (lane >> 3);
  const int kblk_g = (lane & 7) ^ (lane >> 3);
  const ushort* Ag = A + (i64)(m0 + srow) * K + (kblk_g << 3);
  const ushort* Wg = W + (i64)(n0 + srow) * K + (kblk_g << 3);
  char* lA = (char*)As + (wave << 12);
  char* lB = (char*)Ws + (wave << 12);

#pragma unroll
  for (int i = 0; i < 4; i++) {
    gload_lds16(Ag + (i64)(i * 8) * K, lA + i * 1024);
    gload_lds16(Wg + (i64)(i * 8) * K, lB + i * 1024);
  }

  for (int k0 = 0; k0 < K; k0 += 64) {
    __syncthreads();
    bf16x8 af[2][4], bf[2][4];
#pragma unroll
    for (int kh = 0; kh < 2; kh++) {
      const int kb = (kh << 2) + (lane >> 4);
#pragma unroll
      for (int m = 0; m < 4; m++) {
        const int row = (wr << 6) + (m << 4) + (lane & 15);
        af[kh][m] = *(const bf16x8*)&As[row * 64 + ((kb ^ (row & 7)) << 3)];
      }
#pragma unroll
      for (int n = 0; n < 4; n++) {
        const int row = (wc << 6) + (n << 4) + (lane & 15);
        bf[kh][n] = *(const bf16x8*)&Ws[row * 64 + ((kb ^ (row & 7)) << 3)];
      }
    }
    __syncthreads();
    if (k0 + 64 < K) {
#pragma unroll
      for (int i = 0; i < 4; i++) {
        gload_lds16(Ag + (k0 + 64) + (i64)(i * 8) * K, lA + i * 1024);
        gload_lds16(Wg + (k0 + 64) + (i64)(i * 8) * K, lB + i * 1024);
      }
    }
#pragma unroll
    for (int kh = 0; kh < 2; kh++)
#pragma unroll
      for (int m = 0; m < 4; m++)
#pragma unroll
        for (int n = 0; n < 4; n++)
          acc[m][n] = __builtin_amdgcn_mfma_f32_16x16x32_bf16(bf[kh][n], af[kh][m], acc[m][n], 0, 0, 0);
  }

#pragma unroll
  for (int m = 0; m < 4; m++) {
    const int row = m0 + (wr << 6) + (m << 4) + (lane & 15);
#pragma unroll
    for (int n = 0; n < 4; n++) {
      const int col = n0 + (wc << 6) + (n << 4) + ((lane >> 4) << 2);
      float v0 = acc[m][n][0], v1 = acc[m][n][1], v2 = acc[m][n][2], v3 = acc[m][n][3];
      if (MODE > 0) {
        const f32x4 bv = *(const f32x4*)&bias[col];
        v0 += bv[0]; v1 += bv[1]; v2 += bv[2]; v3 += bv[3];
      }
      if (MODE == 2) {
        v0 = fmaxf(v0, 0.f); v1 = fmaxf(v1, 0.f);
        v2 = fmaxf(v2, 0.f); v3 = fmaxf(v3, 0.f);
      }
      uint2 o; o.x = pack2(v0, v1); o.y = pack2(v2, v3);
      *(uint2*)&C[(i64)row * N + col] = o;
    }
  }
}

// -------- Fused GEMM + residual + LayerNorm (N = 256 fixed) -------------------
// C = LN(R + A@W^T + bias)*g + b.  R/C have runtime row strides (in elements).
template <int K>
__global__ __launch_bounds__(512) void gemm_ln_k(const ushort* __restrict__ A,
                                                 const ushort* __restrict__ W,
                                                 const float* __restrict__ bias,
                                                 const ushort* R, int rstride,
                                                 const float* __restrict__ g,
                                                 const float* __restrict__ b,
                                                 ushort* C, int cstride, int M) {
  __shared__ ushort As[128 * 64];
  __shared__ ushort Ws[256 * 64];
  __shared__ float partS[128][4];
  __shared__ float partQ[128][4];
  const int tid = threadIdx.x;
  const int wave = tid >> 6, lane = tid & 63;
  const int m0 = blockIdx.x << 7;
  const int wr = wave >> 2, wc = wave & 3;

  f32x4 acc[4][4];
#pragma unroll
  for (int m = 0; m < 4; m++)
#pragma unroll
    for (int n = 0; n < 4; n++) acc[m][n] = (f32x4){0.f, 0.f, 0.f, 0.f};

  int rowA[2], kgA[2];
#pragma unroll
  for (int i = 0; i < 2; i++) {
    const int u = wave * 128 + i * 64 + lane;
    rowA[i] = u >> 3; kgA[i] = (u & 7) ^ ((u >> 3) & 7);
  }
  int rowW[4], kgW[4];
#pragma unroll
  for (int i = 0; i < 4; i++) {
    const int u = wave * 256 + i * 64 + lane;
    rowW[i] = u >> 3; kgW[i] = (u & 7) ^ ((u >> 3) & 7);
  }

#pragma unroll
  for (int i = 0; i < 2; i++)
    gload_lds16(A + (i64)(m0 + rowA[i]) * K + (kgA[i] << 3),
                (char*)As + (wave * 128 + i * 64) * 16);
#pragma unroll
  for (int i = 0; i < 4; i++)
    gload_lds16(W + (i64)rowW[i] * K + (kgW[i] << 3),
                (char*)Ws + (wave * 256 + i * 64) * 16);

  for (int k0 = 0; k0 < K; k0 += 64) {
    __syncthreads();
    bf16x8 af[2][4], bf[2][4];
#pragma unroll
    for (int kh = 0; kh < 2; kh++) {
      const int kb = (kh << 2) + (lane >> 4);
#pragma unroll
      for (int m = 0; m < 4; m++) {
        const int row = (wr << 6) + (m << 4) + (lane & 15);
        af[kh][m] = *(const bf16x8*)&As[row * 64 + ((kb ^ (row & 7)) << 3)];
      }
#pragma unroll
      for (int n = 0; n < 4; n++) {
        const int row = (wc << 6) + (n << 4) + (lane & 15);
        bf[kh][n] = *(const bf16x8*)&Ws[row * 64 + ((kb ^ (row & 7)) << 3)];
      }
    }
    __syncthreads();
    if (k0 + 64 < K) {
#pragma unroll
      for (int i = 0; i < 2; i++)
        gload_lds16(A + (i64)(m0 + rowA[i]) * K + (k0 + 64) + (kgA[i] << 3),
                    (char*)As + (wave * 128 + i * 64) * 16);
#pragma unroll
      for (int i = 0; i < 4; i++)
        gload_lds16(W + (i64)rowW[i] * K + (k0 + 64) + (kgW[i] << 3),
                    (char*)Ws + (wave * 256 + i * 64) * 16);
    }
#pragma unroll
    for (int kh = 0; kh < 2; kh++)
#pragma unroll
      for (int m = 0; m < 4; m++)
#pragma unroll
        for (int n = 0; n < 4; n++)
          acc[m][n] = __builtin_amdgcn_mfma_f32_16x16x32_bf16(bf[kh][n], af[kh][m], acc[m][n], 0, 0, 0);
  }

#pragma unroll
  for (int m = 0; m < 4; m++) {
    const int tokl = (wr << 6) + (m << 4) + (lane & 15);
    const i64 row = (i64)(m0 + tokl);
    float s = 0.f, q = 0.f;
#pragma unroll
    for (int n = 0; n < 4; n++) {
      const int col = (wc << 6) + (n << 4) + ((lane >> 4) << 2);
      const f32x4 bv = *(const f32x4*)&bias[col];
      const uint2 ru = *(const uint2*)&R[row * rstride + col];
      float v0 = acc[m][n][0] + bv[0] + b2f((ushort)(ru.x & 0xffff));
      float v1 = acc[m][n][1] + bv[1] + b2f((ushort)(ru.x >> 16));
      float v2 = acc[m][n][2] + bv[2] + b2f((ushort)(ru.y & 0xffff));
      float v3 = acc[m][n][3] + bv[3] + b2f((ushort)(ru.y >> 16));
      acc[m][n][0] = v0; acc[m][n][1] = v1; acc[m][n][2] = v2; acc[m][n][3] = v3;
      s += v0 + v1 + v2 + v3;
      q += v0 * v0 + v1 * v1 + v2 * v2 + v3 * v3;
    }
    s += __shfl_xor(s, 16, 64); s += __shfl_xor(s, 32, 64);
    q += __shfl_xor(q, 16, 64); q += __shfl_xor(q, 32, 64);
    if (lane < 16) { partS[tokl][wc] = s; partQ[tokl][wc] = q; }
  }
  __syncthreads();
#pragma unroll
  for (int m = 0; m < 4; m++) {
    const int tokl = (wr << 6) + (m << 4) + (lane & 15);
    const i64 row = (i64)(m0 + tokl);
    const f32x4 s4 = *(const f32x4*)&partS[tokl][0];
    const f32x4 q4 = *(const f32x4*)&partQ[tokl][0];
    const float mean = (s4[0] + s4[1] + s4[2] + s4[3]) * (1.f / 256.f);
    const float var = (q4[0] + q4[1] + q4[2] + q4[3]) * (1.f / 256.f) - mean * mean;
    const float rs = rsqrtf(var + 1e-5f);
#pragma unroll
    for (int n = 0; n < 4; n++) {
      const int col = (wc << 6) + (n << 4) + ((lane >> 4) << 2);
      const f32x4 g4 = *(const f32x4*)&g[col];
      const f32x4 b4 = *(const f32x4*)&b[col];
      uint2 o;
      o.x = pack2((acc[m][n][0] - mean) * rs * g4[0] + b4[0],
                  (acc[m][n][1] - mean) * rs * g4[1] + b4[1]);
      o.y = pack2((acc[m][n][2] - mean) * rs * g4[2] + b4[2],
                  (acc[m][n][3] - mean) * rs * g4[3] + b4[3]);
      *(uint2*)&C[row * cstride + col] = o;
    }
  }
}

// ---- Layer-1 attention: thread = (head, query, d-quarter), blockDim = 16*S ---
template <int S, bool ISV2E>
__global__ __launch_bounds__(16 * S) void attn1_k(const ushort* __restrict__ QKV,
                                                  const int* __restrict__ mask,
                                                  ushort* __restrict__ O, int seq0) {
  __shared__ float KL[4][S][68];
  __shared__ float VL[4][S][68];
  const int tid = threadIdx.x;
  const int seq = blockIdx.x;
  const i64 base = (i64)seq * S;
  const int gseq = seq0 + seq;

  // stage K,V (bf16 global -> f32 LDS), 4-dim units
  for (int u = tid; u < 128 * S; u += 16 * S) {
    const int d4 = u & 15, h = (u >> 4) & 3, mt = u >> 6;
    const int mat = (mt >= S), t = mat ? mt - S : mt;
    const ushort* gp = QKV + (base + t) * 768 + 256 + mat * 256 + h * 64 + d4 * 4;
    ushort4 raw = *(const ushort4*)gp;
    float* dst = (mat ? &VL[h][t][0] : &KL[h][t][0]) + d4 * 4;
    dst[0] = b2f(raw.x); dst[1] = b2f(raw.y); dst[2] = b2f(raw.z); dst[3] = b2f(raw.w);
  }
  __syncthreads();

  const int h = tid / (4 * S);
  const int r = tid - h * 4 * S;
  const int q = r >> 2, j = r & 3;

  // Q slice (16 dims) straight from global
  float qv[16];
  {
    const ushort* qp = QKV + (base + q) * 768 + h * 64 + j * 16;
    cvt8(*(const uint4*)qp, qv);
    cvt8(*(const uint4*)(qp + 8), qv + 8);
  }

  float w[S];
  float mx = -1e30f;
#pragma unroll
  for (int s = 0; s < S; s++) {
    const bool valid = ISV2E ? (s == 0 || mask[(i64)gseq * ARITY + (s - 1)] != 0)
                             : (mask[(i64)gseq * S + s] != 0);
    const float* kr = &KL[h][s][j * 16];
    float p = 0.f;
#pragma unroll
    for (int e = 0; e < 4; e++) {
      const float4 kv = *(const float4*)(kr + e * 4);
      p = fmaf(qv[e * 4 + 0], kv.x, p);
      p = fmaf(qv[e * 4 + 1], kv.y, p);
      p = fmaf(qv[e * 4 + 2], kv.z, p);
      p = fmaf(qv[e * 4 + 3], kv.w, p);
    }
    p += __shfl_xor(p, 1, 64);
    p += __shfl_xor(p, 2, 64);
    w[s] = valid ? p * 0.125f : -1e9f;
    mx = fmaxf(mx, w[s]);
  }
  float sum = 0.f;
#pragma unroll
  for (int s = 0; s < S; s++) { w[s] = __expf(w[s] - mx); sum += w[s]; }
  const float inv = 1.f / sum;

  float o[16];
#pragma unroll
  for (int e = 0; e < 16; e++) o[e] = 0.f;
#pragma unroll
  for (int s = 0; s < S; s++) {
    const float ws = w[s];
    const float* vr = &VL[h][s][j * 16];
#pragma unroll
    for (int e = 0; e < 4; e++) {
      const float4 vv = *(const float4*)(vr + e * 4);
      o[e * 4 + 0] = fmaf(ws, vv.x, o[e * 4 + 0]);
      o[e * 4 + 1] = fmaf(ws, vv.y, o[e * 4 + 1]);
      o[e * 4 + 2] = fmaf(ws, vv.z, o[e * 4 + 2]);
      o[e * 4 + 3] = fmaf(ws, vv.w, o[e * 4 + 3]);
    }
  }
  uint4 st0, st1;
  st0.x = pack2(o[0] * inv, o[1] * inv);   st0.y = pack2(o[2] * inv, o[3] * inv);
  st0.z = pack2(o[4] * inv, o[5] * inv);   st0.w = pack2(o[6] * inv, o[7] * inv);
  st1.x = pack2(o[8] * inv, o[9] * inv);   st1.y = pack2(o[10] * inv, o[11] * inv);
  st1.z = pack2(o[12] * inv, o[13] * inv); st1.w = pack2(o[14] * inv, o[15] * inv);
  ushort* op = O + (base + q) * 256 + h * 64 + j * 16;
  *(uint4*)op = st0;
  *(uint4*)(op + 8) = st1;
}

// ---- Layer-2 attention, CLS query only. thread = (seq_l, head, d-quarter) ----
// 16 seqs per 256-thread block; O_cls is compact [nSeq, 256].
template <int S, bool ISV2E>
__global__ __launch_bounds__(256) void attn_cls_k(const ushort* __restrict__ QKV,
                                                  const int* __restrict__ mask,
                                                  ushort* __restrict__ Ocls, int seq0) {
  const int tid = threadIdx.x;
  const int sl = tid >> 4, h = (tid >> 2) & 3, j = tid & 3;
  const int seq = blockIdx.x * 16 + sl;
  const i64 base = (i64)seq * S;
  const int gseq = seq0 + seq;

  float qv[16];
  {
    const ushort* qp = QKV + base * 768 + h * 64 + j * 16;
    cvt8(*(const uint4*)qp, qv);
    cvt8(*(const uint4*)(qp + 8), qv + 8);
  }
  float w[S];
  float mx = -1e30f;
#pragma unroll
  for (int s = 0; s < S; s++) {
    const bool valid = ISV2E ? (s == 0 || mask[(i64)gseq * ARITY + (s - 1)] != 0)
                             : (mask[(i64)gseq * S + s] != 0);
    float kf[16];
    const ushort* kp = QKV + (base + s) * 768 + 256 + h * 64 + j * 16;
    cvt8(*(const uint4*)kp, kf);
    cvt8(*(const uint4*)(kp + 8), kf + 8);
    float p = 0.f;
#pragma unroll
    for (int e = 0; e < 16; e++) p = fmaf(qv[e], kf[e], p);
    p += __shfl_xor(p, 1, 64);
    p += __shfl_xor(p, 2, 64);
    w[s] = valid ? p * 0.125f : -1e9f;
    mx = fmaxf(mx, w[s]);
  }
  float sum = 0.f;
#pragma unroll
  for (int s = 0; s < S; s++) { w[s] = __expf(w[s] - mx); sum += w[s]; }
  const float inv = 1.f / sum;

  float o[16];
#pragma unroll
  for (int e = 0; e < 16; e++) o[e] = 0.f;
#pragma unroll
  for (int s = 0; s < S; s++) {
    float vf[16];
    const ushort* vp = QKV + (base + s) * 768 + 512 + h * 64 + j * 16;
    cvt8(*(const uint4*)vp, vf);
    cvt8(*(const uint4*)(vp + 8), vf + 8);
    const float ws = w[s];
#pragma unroll
    for (int e = 0; e < 16; e++) o[e] = fmaf(ws, vf[e], o[e]);
  }
  uint4 st0, st1;
  st0.x = pack2(o[0] * inv, o[1] * inv);   st0.y = pack2(o[2] * inv, o[3] * inv);
  st0.z = pack2(o[4] * inv, o[5] * inv);   st0.w = pack2(o[6] * inv, o[7] * inv);
  st1.x = pack2(o[8] * inv, o[9] * inv);   st1.y = pack2(o[10] * inv, o[11] * inv);
  st1.z = pack2(o[12] * inv, o[13] * inv); st1.w = pack2(o[14] * inv, o[15] * inv);
  ushort* op = Ocls + (i64)seq * 256 + h * 64 + j * 16;
  *(uint4*)op = st0;
  *(uint4*)(op + 8) = st1;
}

// ---------------- Gathers / scatters / conversion -----------------------------
__global__ __launch_bounds__(256) void f2b_cvt_k(const float* __restrict__ in,
                                                 ushort* __restrict__ out, int n) {
  for (int i = blockIdx.x * 256 + threadIdx.x; i < n; i += gridDim.x * 256)
    out[i] = f2b(in[i]);
}

__global__ __launch_bounds__(256) void gather_v2e_k(const float* __restrict__ unity,
                                                    const float* __restrict__ pos,
                                                    const int* __restrict__ xid,
                                                    const int* __restrict__ xpos,
                                                    ushort* __restrict__ X, int e0) {
  const int tk = blockIdx.x * 4 + (threadIdx.x >> 6);
  const int lane = threadIdx.x & 63;
  const int el = tk / SV, t = tk - el * SV;
  const int e = e0 + el;
  float4 v = make_float4(0.f, 0.f, 0.f, 0.f);
  if (t > 0) {
    const int id = xid[(i64)e * ARITY + (t - 1)];
    v = *(const float4*)&unity[(i64)id * 256 + lane * 4];
  }
  const int pp = xpos[(i64)e * SV + t];
  const float4 pv = *(const float4*)&pos[(i64)pp * 256 + lane * 4];
  uint2 o;
  o.x = pack2(v.x + pv.x, v.y + pv.y);
  o.y = pack2(v.z + pv.z, v.w + pv.w);
  *(uint2*)&X[(i64)tk * 256 + lane * 4] = o;
}

__global__ __launch_bounds__(256) void gather_e2v_k(const ushort* __restrict__ ext,
                                                    const int* __restrict__ hid,
                                                    ushort* __restrict__ X, int n0) {
  const int tk = blockIdx.x * 4 + (threadIdx.x >> 6);
  const int lane = threadIdx.x & 63;
  const int nl = tk / SE, j = tk - nl * SE;
  const int n = n0 + nl;
  const int id = hid[(i64)n * SE + j];
  *(uint2*)&X[(i64)tk * 256 + lane * 4] =
      *(const uint2*)&ext[(i64)id * 256 + lane * 4];
}

__global__ __launch_bounds__(256) void scatter_k(const ushort* __restrict__ Xc,
                                                 const int* __restrict__ subg,
                                                 float* __restrict__ unity, int n0) {
  const int nl = blockIdx.x * 4 + (threadIdx.x >> 6);
  const int lane = threadIdx.x & 63;
  const int dst = subg[n0 + nl];
  ushort4 v = *(const ushort4*)&Xc[(i64)nl * 256 + lane * 4];
  float4 o; o.x = b2f(v.x); o.y = b2f(v.y); o.z = b2f(v.z); o.w = b2f(v.w);
  *(float4*)&unity[(i64)dst * 256 + lane * 4] = o;
}

__global__ __launch_bounds__(256) void ext_init_k(ushort* __restrict__ ext,
                                                  const float* __restrict__ pad,
                                                  const float* __restrict__ cls) {
  const int d = threadIdx.x;
  ext[(i64)NHEDGE * 256 + d] = f2b(pad[d]);
  ext[(i64)(NHEDGE + 1) * 256 + d] = f2b(cls[d]);
}

__global__ __launch_bounds__(256) void out_gather_k(const ushort* __restrict__ ext,
                                                    const int* __restrict__ pred,
                                                    float* __restrict__ out) {
  const int i = blockIdx.x * 4 + (threadIdx.x >> 6);
  const int lane = threadIdx.x & 63;
  const int e = pred[i];
  ushort4 v = *(const ushort4*)&ext[(i64)e * 256 + lane * 4];
  float4 o; o.x = b2f(v.x); o.y = b2f(v.y); o.z = b2f(v.z); o.w = b2f(v.w);
  *(float4*)&out[(i64)i * 256 + lane * 4] = o;
}

// ---------------- Host orchestration ------------------------------------------
extern "C" void kernel_launch(void* const* d_in, const int* in_sizes, int n_in,
                              void* d_out, int out_size, void* d_ws, size_t ws_size,
                              hipStream_t stream) {
  (void)in_sizes; (void)n_in; (void)out_size;
  const float* unity_in = (const float*)d_in[0];
  const float* cls_emb  = (const float*)d_in[1];
  const float* pad_emb  = (const float*)d_in[2];
  const float* pos_tab  = (const float*)d_in[3];
  const float* qkv_w    = (const float*)d_in[4];
  const float* qkv_b    = (const float*)d_in[5];
  const float* out_w    = (const float*)d_in[6];
  const float* out_b    = (const float*)d_in[7];
  const float* ln1_g    = (const float*)d_in[8];
  const float* ln1_b    = (const float*)d_in[9];
  const float* ln2_g    = (const float*)d_in[10];
  const float* ln2_b    = (const float*)d_in[11];
  const float* ff1_w    = (const float*)d_in[12];
  const float* ff1_b    = (const float*)d_in[13];
  const float* ff2_w    = (const float*)d_in[14];
  const float* ff2_b    = (const float*)d_in[15];
  const int* xid   = (const int*)d_in[16];
  const int* vmask = (const int*)d_in[17];
  const int* xpos  = (const int*)d_in[18];
  const int* hid   = (const int*)d_in[19];
  const int* hmask = (const int*)d_in[20];
  const int* subg  = (const int*)d_in[21];
  const int* pred  = (const int*)d_in[22];

  const i64 unity_b = (i64)NTOTAL * 256 * 4;
  const i64 ext_b   = (i64)(NHEDGE + 2) * 256 * 2;
  const int nq = 2 * 768 * 256, no = 2 * 256 * 256,
            n1 = 2 * 1024 * 256, n2 = 2 * 256 * 1024;
  const i64 wts_b = (i64)(nq + no + n1 + n2) * 2;
  const i64 per_elem = (i64)SE * (512 + 2048 + 512);  // X+Y+O bytes
  int CHUNK = 8192;
  while (CHUNK > 128 && unity_b + ext_b + wts_b + (i64)CHUNK * per_elem > (i64)ws_size)
    CHUNK >>= 1;

  char* w = (char*)d_ws;
  float*  unity = (float*)w;  w += unity_b;
  ushort* ext   = (ushort*)w; w += ext_b;
  ushort* wq    = (ushort*)w; w += (i64)nq * 2;
  ushort* wo    = (ushort*)w; w += (i64)no * 2;
  ushort* w1    = (ushort*)w; w += (i64)n1 * 2;
  ushort* w2    = (ushort*)w; w += (i64)n2 * 2;
  ushort* X     = (ushort*)w; w += (i64)CHUNK * SE * 256 * 2;
  ushort* Y     = (ushort*)w; w += (i64)CHUNK * SE * 1024 * 2;
  ushort* O     = (ushort*)w; w += (i64)CHUNK * SE * 256 * 2;
  // layer-2 compact buffers carved from O (free during layer 2)
  ushort* Ocls = O;
  ushort* X2   = O + (i64)CHUNK * 256;
  ushort* X3   = O + (i64)2 * CHUNK * 256;

  f2b_cvt_k<<<512, 256, 0, stream>>>(qkv_w, wq, nq);
  f2b_cvt_k<<<512, 256, 0, stream>>>(out_w, wo, no);
  f2b_cvt_k<<<512, 256, 0, stream>>>(ff1_w, w1, n1);
  f2b_cvt_k<<<512, 256, 0, stream>>>(ff2_w, w2, n2);
  hipMemcpyAsync(unity, unity_in, unity_b, hipMemcpyDeviceToDevice, stream);
  ext_init_k<<<1, 256, 0, stream>>>(ext, pad_emb, cls_emb);

  for (int k = 0; k <= 2; k++) {
    // ---- V2E ----
    for (int c = 0; c < NHEDGE / CHUNK; c++) {
      const int e0 = c * CHUNK;
      const int M = CHUNK * SV;
      gather_v2e_k<<<M / 4, 256, 0, stream>>>(unity, pos_tab, xid, xpos, X, e0);
      // layer 0: full
      gemm_bf16_k<256, 1><<<dim3(6, M / 128), 256, 0, stream>>>(
          X, wq, qkv_b, Y, M, 768);
      attn1_k<SV, true><<<CHUNK, 16 * SV, 0, stream>>>(Y, vmask, O, e0);
      gemm_ln_k<256><<<M / 128, 512, 0, stream>>>(
          O, wo, out_b, X, 256, ln1_g, ln1_b, X, 256, M);
      gemm_bf16_k<256, 2><<<dim3(8, M / 128), 256, 0, stream>>>(
          X, w1, ff1_b, Y, M, 1024);
      gemm_ln_k<1024><<<M / 128, 512, 0, stream>>>(
          Y, w2, ff2_b, X, 256, ln2_g, ln2_b, X, 256, M);
      // layer 1: CLS-only tail
      gemm_bf16_k<256, 1><<<dim3(6, M / 128), 256, 0, stream>>>(
          X, wq + (i64)768 * 256, qkv_b + 768, Y, M, 768);
      attn_cls_k<SV, true><<<CHUNK / 16, 256, 0, stream>>>(Y, vmask, Ocls, e0);
      gemm_ln_k<256><<<CHUNK / 128, 512, 0, stream>>>(
          Ocls, wo + (i64)256 * 256, out_b + 256, X, SV * 256,
          ln1_g + 256, ln1_b + 256, X2, 256, CHUNK);
      gemm_bf16_k<256, 2><<<dim3(8, CHUNK / 128), 256, 0, stream>>>(
          X2, w1 + (i64)1024 * 256, ff1_b + 1024, Y, CHUNK, 1024);
      gemm_ln_k<1024><<<CHUNK / 128, 512, 0, stream>>>(
          Y, w2 + (i64)256 * 1024, ff2_b + 256, X2, 256,
          ln2_g + 256, ln2_b + 256, ext + (i64)e0 * 256, 256, CHUNK);
    }
    // ---- E2V ----
    if (k < 2) {
      for (int c = 0; c < NNODE / CHUNK; c++) {
        const int n0 = c * CHUNK;
        const int M = CHUNK * SE;
        gather_e2v_k<<<M / 4, 256, 0, stream>>>(ext, hid, X, n0);
        // layer 0: full
        gemm_bf16_k<256, 1><<<dim3(6, M / 128), 256, 0, stream>>>(
            X, wq, qkv_b, Y, M, 768);
        attn1_k<SE, false><<<CHUNK, 16 * SE, 0, stream>>>(Y, hmask, O, n0);
        gemm_ln_k<256><<<M / 128, 512, 0, stream>>>(
            O, wo, out_b, X, 256, ln1_g, ln1_b, X, 256, M);
        gemm_bf16_k<256, 2><<<dim3(8, M / 128), 256, 0, stream>>>(
            X, w1, ff1_b, Y, M, 1024);
        gemm_ln_k<1024><<<M / 128, 512, 0, stream>>>(
            Y, w2, ff2_b, X, 256, ln2_g, ln2_b, X, 256, M);
        // layer 1: CLS-only tail
        gemm_bf16_k<256, 1><<<dim3(6, M / 128), 256, 0, stream>>>(
            X, wq + (i64)768 * 256, qkv_b + 768, Y, M, 768);
        attn_cls_k<SE, false><<<CHUNK / 16, 256, 0, stream>>>(Y, hmask, Ocls, n0);
        gemm_ln_k<256><<<CHUNK / 128, 512, 0, stream>>>(
            Ocls, wo + (i64)256 * 256, out_b + 256, X, SE * 256,
            ln1_g + 256, ln1_b + 256, X2, 256, CHUNK);
        gemm_bf16_k<256, 2><<<dim3(8, CHUNK / 128), 256, 0, stream>>>(
            X2, w1 + (i64)1024 * 256, ff1_b + 1024, Y, CHUNK, 1024);
        gemm_ln_k<1024><<<CHUNK / 128, 512, 0, stream>>>(
            Y, w2 + (i64)256 * 1024, ff2_b + 256, X2, 256,
            ln2_g + 256, ln2_b + 256, X3, 256, CHUNK);
        scatter_k<<<CHUNK / 4, 256, 0, stream>>>(X3, subg, unity, n0);
      }
    }
  }
  out_gather_k<<<64, 256, 0, stream>>>(ext, pred, (float*)d_out);
}

// Round 7
// 19355.632 us; speedup vs baseline: 8.0300x; 1.1535x over previous
//
#include <hip/hip_runtime.h>
#include <stdint.h>

typedef long long i64;
typedef __attribute__((ext_vector_type(8))) short bf16x8;
typedef __attribute__((ext_vector_type(4))) float f32x4;

#define SV 11
#define SE 17
#define ARITY 10
#define NHEDGE 32768
#define NNODE 65536
#define NTOTAL 100000

__device__ __forceinline__ float b2f(ushort u) {
  union { uint32_t i; float f; } v; v.i = (uint32_t)u << 16; return v.f;
}
__device__ __forceinline__ ushort f2b(float f) {
  union { float f; uint32_t i; } v; v.f = f;
  uint32_t u = v.i + 0x7fffu + ((v.i >> 16) & 1u);
  return (ushort)(u >> 16);
}
__device__ __forceinline__ uint pack2(float a, float b) {
  return (uint)f2b(a) | ((uint)f2b(b) << 16);
}
__device__ __forceinline__ void cvt8(uint4 v, float* f) {
  f[0] = b2f((ushort)(v.x & 0xffff)); f[1] = b2f((ushort)(v.x >> 16));
  f[2] = b2f((ushort)(v.y & 0xffff)); f[3] = b2f((ushort)(v.y >> 16));
  f[4] = b2f((ushort)(v.z & 0xffff)); f[5] = b2f((ushort)(v.z >> 16));
  f[6] = b2f((ushort)(v.w & 0xffff)); f[7] = b2f((ushort)(v.w >> 16));
}

__device__ __forceinline__ void gload_lds16(const void* g, void* l) {
  __builtin_amdgcn_global_load_lds((const __attribute__((address_space(1))) void*)g,
                                   (__attribute__((address_space(3))) void*)l, 16, 0, 0);
}

__device__ __forceinline__ int xcd_swizzle(int orig, int nwg) {
  const int xcd = orig & 7, rest = orig >> 3;
  const int q = nwg >> 3, r = nwg & 7;
  return (xcd < r ? xcd * (q + 1) : r * (q + 1) + (xcd - r) * q) + rest;
}

// ================= compaction: count / scan / fill =============================
__global__ __launch_bounds__(256) void cnt_k(const int* __restrict__ mask, int width,
                                             int extra, int* __restrict__ cnt, int n) {
  const int i = blockIdx.x * 256 + threadIdx.x;
  if (i >= n) return;
  int c = extra;
  for (int j = 0; j < width; j++) c += (mask[(i64)i * width + j] != 0);
  cnt[i] = c;
}

__global__ __launch_bounds__(256) void scan1_k(const int* __restrict__ cnt,
                                               int* __restrict__ ss,
                                               int* __restrict__ part, int n) {
  __shared__ int sm[256];
  const int i = blockIdx.x * 256 + threadIdx.x;
  const int v = (i < n) ? cnt[i] : 0;
  sm[threadIdx.x] = v;
  __syncthreads();
  for (int o = 1; o < 256; o <<= 1) {
    const int t = (threadIdx.x >= o) ? sm[threadIdx.x - o] : 0;
    __syncthreads();
    sm[threadIdx.x] += t;
    __syncthreads();
  }
  if (i < n) ss[i] = sm[threadIdx.x] - v;  // exclusive
  if (threadIdx.x == 255) part[blockIdx.x] = sm[255];
}

__global__ __launch_bounds__(256) void scan2_k(int* __restrict__ part, int nb,
                                               int* __restrict__ ss, int n) {
  __shared__ int sm[256];
  const int v = (threadIdx.x < nb) ? part[threadIdx.x] : 0;
  sm[threadIdx.x] = v;
  __syncthreads();
  for (int o = 1; o < 256; o <<= 1) {
    const int t = (threadIdx.x >= o) ? sm[threadIdx.x - o] : 0;
    __syncthreads();
    sm[threadIdx.x] += t;
    __syncthreads();
  }
  if (threadIdx.x < nb) part[threadIdx.x] = sm[threadIdx.x] - v;
  if (threadIdx.x == 255) ss[n] = sm[255];
}

// add block offsets into ss; emit token codes (seq<<5 | slot), slot order kept.
__global__ __launch_bounds__(256) void scan3_k(int* __restrict__ ss,
                                               const int* __restrict__ part,
                                               const int* __restrict__ mask, int width,
                                               int extra, int* __restrict__ tok, int n) {
  const int i = blockIdx.x * 256 + threadIdx.x;
  if (i >= n) return;
  int off = ss[i] + part[blockIdx.x];
  ss[i] = off;
  if (extra) {  // V2E: slot 0 = CLS always valid; mask covers slots 1..width
    tok[off++] = (i << 5);
    for (int j = 0; j < width; j++)
      if (mask[(i64)i * width + j] != 0) tok[off++] = (i << 5) | (j + 1);
  } else {      // E2V: mask covers all slots incl CLS col
    for (int j = 0; j < width; j++)
      if (mask[(i64)i * width + j] != 0) tok[off++] = (i << 5) | j;
  }
}

// ================= bf16 MFMA GEMM =============================================
// C[M,N] = act(A@W^T + bias). ssn!=null -> Mv=ssn[nseq]-ssn[0] early-exit.
// arp!=null -> A row m comes from row (arp[m]-arp[0]) (CLS gather).
template <int K, int MODE>
__global__ __launch_bounds__(256) void gemm_bf16_k(const ushort* __restrict__ A,
                                                   const ushort* __restrict__ W,
                                                   const float* __restrict__ bias,
                                                   ushort* __restrict__ C, int M, int N,
                                                   const int* ssn, int nseq,
                                                   const int* arp) {
  const int tid = threadIdx.x;
  const int wave = tid >> 6, lane = tid & 63;
  const int nwg = gridDim.x * gridDim.y;
  const int wg = xcd_swizzle(blockIdx.y * gridDim.x + blockIdx.x, nwg);
  const int bx = wg % gridDim.x, by = wg / gridDim.x;
  const int m0 = by << 7, n0 = bx << 7;
  if (ssn && m0 >= ssn[nseq] - ssn[0]) return;
  __shared__ ushort As[128 * 64];
  __shared__ ushort Ws[128 * 64];
  const int wr = wave >> 1, wc = wave & 1;

  f32x4 acc[4][4];
#pragma unroll
  for (int m = 0; m < 4; m++)
#pragma unroll
    for (int n = 0; n < 4; n++) acc[m][n] = (f32x4){0.f, 0.f, 0.f, 0.f};

  const int srow = (wave << 5) + (lane >> 3);
  const int kblk_g = (lane & 7) ^ (lane >> 3);
  const i64 arow = arp ? (i64)(arp[m0 + srow] - arp[0]) : (i64)(m0 + srow);
  const ushort* Ag = A + arow * K + (kblk_g << 3);
  const ushort* Wg = W + (i64)(n0 + srow) * K + (kblk_g << 3);
  char* lA = (char*)As + (wave << 12);
  char* lB = (char*)Ws + (wave << 12);

#pragma unroll
  for (int i = 0; i < 4; i++) {
    gload_lds16(Ag + (i64)(i * 8) * K, lA + i * 1024);
    gload_lds16(Wg + (i64)(i * 8) * K, lB + i * 1024);
  }

  for (int k0 = 0; k0 < K; k0 += 64) {
    __syncthreads();
    bf16x8 af[2][4], bf[2][4];
#pragma unroll
    for (int kh = 0; kh < 2; kh++) {
      const int kb = (kh << 2) + (lane >> 4);
#pragma unroll
      for (int m = 0; m < 4; m++) {
        const int row = (wr << 6) + (m << 4) + (lane & 15);
        af[kh][m] = *(const bf16x8*)&As[row * 64 + ((kb ^ (row & 7)) << 3)];
      }
#pragma unroll
      for (int n = 0; n < 4; n++) {
        const int row = (wc << 6) + (n << 4) + (lane & 15);
        bf[kh][n] = *(const bf16x8*)&Ws[row * 64 + ((kb ^ (row & 7)) << 3)];
      }
    }
    __syncthreads();
    if (k0 + 64 < K) {
#pragma unroll
      for (int i = 0; i < 4; i++) {
        gload_lds16(Ag + (k0 + 64) + (i64)(i * 8) * K, lA + i * 1024);
        gload_lds16(Wg + (k0 + 64) + (i64)(i * 8) * K, lB + i * 1024);
      }
    }
#pragma unroll
    for (int kh = 0; kh < 2; kh++)
#pragma unroll
      for (int m = 0; m < 4; m++)
#pragma unroll
        for (int n = 0; n < 4; n++)
          acc[m][n] = __builtin_amdgcn_mfma_f32_16x16x32_bf16(bf[kh][n], af[kh][m], acc[m][n], 0, 0, 0);
  }

#pragma unroll
  for (int m = 0; m < 4; m++) {
    const int row = m0 + (wr << 6) + (m << 4) + (lane & 15);
#pragma unroll
    for (int n = 0; n < 4; n++) {
      const int col = n0 + (wc << 6) + (n << 4) + ((lane >> 4) << 2);
      float v0 = acc[m][n][0], v1 = acc[m][n][1], v2 = acc[m][n][2], v3 = acc[m][n][3];
      if (MODE > 0) {
        const f32x4 bv = *(const f32x4*)&bias[col];
        v0 += bv[0]; v1 += bv[1]; v2 += bv[2]; v3 += bv[3];
      }
      if (MODE == 2) {
        v0 = fmaxf(v0, 0.f); v1 = fmaxf(v1, 0.f);
        v2 = fmaxf(v2, 0.f); v3 = fmaxf(v3, 0.f);
      }
      uint2 o; o.x = pack2(v0, v1); o.y = pack2(v2, v3);
      *(uint2*)&C[(i64)row * N + col] = o;
    }
  }
}

// ============ Fused GEMM + residual + LayerNorm (N = 256) ======================
// rrp!=null -> R row m comes from row (rrp[m]-rrp[0]) (CLS residual gather).
template <int K>
__global__ __launch_bounds__(512) void gemm_ln_k(const ushort* __restrict__ A,
                                                 const ushort* __restrict__ W,
                                                 const float* __restrict__ bias,
                                                 const ushort* R, int rstride,
                                                 const float* __restrict__ g,
                                                 const float* __restrict__ b,
                                                 ushort* C, int cstride, int M,
                                                 const int* ssn, int nseq,
                                                 const int* rrp) {
  const int m0 = blockIdx.x << 7;
  if (ssn && m0 >= ssn[nseq] - ssn[0]) return;
  __shared__ ushort As[128 * 64];
  __shared__ ushort Ws[256 * 64];
  __shared__ float partS[128][4];
  __shared__ float partQ[128][4];
  const int tid = threadIdx.x;
  const int wave = tid >> 6, lane = tid & 63;
  const int wr = wave >> 2, wc = wave & 3;

  f32x4 acc[4][4];
#pragma unroll
  for (int m = 0; m < 4; m++)
#pragma unroll
    for (int n = 0; n < 4; n++) acc[m][n] = (f32x4){0.f, 0.f, 0.f, 0.f};

  int rowA[2], kgA[2];
#pragma unroll
  for (int i = 0; i < 2; i++) {
    const int u = wave * 128 + i * 64 + lane;
    rowA[i] = u >> 3; kgA[i] = (u & 7) ^ ((u >> 3) & 7);
  }
  int rowW[4], kgW[4];
#pragma unroll
  for (int i = 0; i < 4; i++) {
    const int u = wave * 256 + i * 64 + lane;
    rowW[i] = u >> 3; kgW[i] = (u & 7) ^ ((u >> 3) & 7);
  }

#pragma unroll
  for (int i = 0; i < 2; i++)
    gload_lds16(A + (i64)(m0 + rowA[i]) * K + (kgA[i] << 3),
                (char*)As + (wave * 128 + i * 64) * 16);
#pragma unroll
  for (int i = 0; i < 4; i++)
    gload_lds16(W + (i64)rowW[i] * K + (kgW[i] << 3),
                (char*)Ws + (wave * 256 + i * 64) * 16);

  for (int k0 = 0; k0 < K; k0 += 64) {
    __syncthreads();
    bf16x8 af[2][4], bf[2][4];
#pragma unroll
    for (int kh = 0; kh < 2; kh++) {
      const int kb = (kh << 2) + (lane >> 4);
#pragma unroll
      for (int m = 0; m < 4; m++) {
        const int row = (wr << 6) + (m << 4) + (lane & 15);
        af[kh][m] = *(const bf16x8*)&As[row * 64 + ((kb ^ (row & 7)) << 3)];
      }
#pragma unroll
      for (int n = 0; n < 4; n++) {
        const int row = (wc << 6) + (n << 4) + (lane & 15);
        bf[kh][n] = *(const bf16x8*)&Ws[row * 64 + ((kb ^ (row & 7)) << 3)];
      }
    }
    __syncthreads();
    if (k0 + 64 < K) {
#pragma unroll
      for (int i = 0; i < 2; i++)
        gload_lds16(A + (i64)(m0 + rowA[i]) * K + (k0 + 64) + (kgA[i] << 3),
                    (char*)As + (wave * 128 + i * 64) * 16);
#pragma unroll
      for (int i = 0; i < 4; i++)
        gload_lds16(W + (i64)rowW[i] * K + (k0 + 64) + (kgW[i] << 3),
                    (char*)Ws + (wave * 256 + i * 64) * 16);
    }
#pragma unroll
    for (int kh = 0; kh < 2; kh++)
#pragma unroll
      for (int m = 0; m < 4; m++)
#pragma unroll
        for (int n = 0; n < 4; n++)
          acc[m][n] = __builtin_amdgcn_mfma_f32_16x16x32_bf16(bf[kh][n], af[kh][m], acc[m][n], 0, 0, 0);
  }

#pragma unroll
  for (int m = 0; m < 4; m++) {
    const int tokl = (wr << 6) + (m << 4) + (lane & 15);
    const int row = m0 + tokl;
    const i64 rr = rrp ? (i64)(rrp[row] - rrp[0]) : (i64)row;
    float s = 0.f, q = 0.f;
#pragma unroll
    for (int n = 0; n < 4; n++) {
      const int col = (wc << 6) + (n << 4) + ((lane >> 4) << 2);
      const f32x4 bv = *(const f32x4*)&bias[col];
      const uint2 ru = *(const uint2*)&R[rr * rstride + col];
      float v0 = acc[m][n][0] + bv[0] + b2f((ushort)(ru.x & 0xffff));
      float v1 = acc[m][n][1] + bv[1] + b2f((ushort)(ru.x >> 16));
      float v2 = acc[m][n][2] + bv[2] + b2f((ushort)(ru.y & 0xffff));
      float v3 = acc[m][n][3] + bv[3] + b2f((ushort)(ru.y >> 16));
      acc[m][n][0] = v0; acc[m][n][1] = v1; acc[m][n][2] = v2; acc[m][n][3] = v3;
      s += v0 + v1 + v2 + v3;
      q += v0 * v0 + v1 * v1 + v2 * v2 + v3 * v3;
    }
    s += __shfl_xor(s, 16, 64); s += __shfl_xor(s, 32, 64);
    q += __shfl_xor(q, 16, 64); q += __shfl_xor(q, 32, 64);
    if (lane < 16) { partS[tokl][wc] = s; partQ[tokl][wc] = q; }
  }
  __syncthreads();
#pragma unroll
  for (int m = 0; m < 4; m++) {
    const int tokl = (wr << 6) + (m << 4) + (lane & 15);
    const i64 row = (i64)(m0 + tokl);
    const f32x4 s4 = *(const f32x4*)&partS[tokl][0];
    const f32x4 q4 = *(const f32x4*)&partQ[tokl][0];
    const float mean = (s4[0] + s4[1] + s4[2] + s4[3]) * (1.f / 256.f);
    const float var = (q4[0] + q4[1] + q4[2] + q4[3]) * (1.f / 256.f) - mean * mean;
    const float rs = rsqrtf(var + 1e-5f);
#pragma unroll
    for (int n = 0; n < 4; n++) {
      const int col = (wc << 6) + (n << 4) + ((lane >> 4) << 2);
      const f32x4 g4 = *(const f32x4*)&g[col];
      const f32x4 b4 = *(const f32x4*)&b[col];
      uint2 o;
      o.x = pack2((acc[m][n][0] - mean) * rs * g4[0] + b4[0],
                  (acc[m][n][1] - mean) * rs * g4[1] + b4[1]);
      o.y = pack2((acc[m][n][2] - mean) * rs * g4[2] + b4[2],
                  (acc[m][n][3] - mean) * rs * g4[3] + b4[3]);
      *(uint2*)&C[row * cstride + col] = o;
    }
  }
}

// ========= Layer-1 attention (compact, mask-free, variable length) ============
template <int S>
__global__ __launch_bounds__(16 * S) void attn1_k(const ushort* __restrict__ QKV,
                                                  const int* __restrict__ ss,
                                                  ushort* __restrict__ O) {
  __shared__ float KL[4][S][68];
  __shared__ float VL[4][S][68];
  const int tid = threadIdx.x;
  const int s0 = ss[0];
  const int base = ss[blockIdx.x] - s0;
  const int L = ss[blockIdx.x + 1] - ss[blockIdx.x];

  for (int u = tid; u < 128 * L; u += 16 * S) {
    const int d4 = u & 15, h = (u >> 4) & 3, mt = u >> 6;
    const int mat = (mt >= L), t = mat ? mt - L : mt;
    const ushort* gp = QKV + (i64)(base + t) * 768 + 256 + mat * 256 + h * 64 + d4 * 4;
    ushort4 raw = *(const ushort4*)gp;
    float* dst = (mat ? &VL[h][t][0] : &KL[h][t][0]) + d4 * 4;
    dst[0] = b2f(raw.x); dst[1] = b2f(raw.y); dst[2] = b2f(raw.z); dst[3] = b2f(raw.w);
  }
  __syncthreads();

  const int h = tid / (4 * S);
  const int r = tid - h * 4 * S;
  const int q = r >> 2, j = r & 3;
  if (q >= L) return;

  float qv[16];
  {
    const ushort* qp = QKV + (i64)(base + q) * 768 + h * 64 + j * 16;
    cvt8(*(const uint4*)qp, qv);
    cvt8(*(const uint4*)(qp + 8), qv + 8);
  }

  float w[S];
  float mx = -1e30f;
#pragma unroll
  for (int s = 0; s < S; s++) {
    float p = -1e30f;
    if (s < L) {
      const float* kr = &KL[h][s][j * 16];
      p = 0.f;
#pragma unroll
      for (int e = 0; e < 4; e++) {
        const float4 kv = *(const float4*)(kr + e * 4);
        p = fmaf(qv[e * 4 + 0], kv.x, p);
        p = fmaf(qv[e * 4 + 1], kv.y, p);
        p = fmaf(qv[e * 4 + 2], kv.z, p);
        p = fmaf(qv[e * 4 + 3], kv.w, p);
      }
      p += __shfl_xor(p, 1, 64);
      p += __shfl_xor(p, 2, 64);
      p *= 0.125f;
    }
    w[s] = p;
    mx = fmaxf(mx, p);
  }
  float sum = 0.f;
#pragma unroll
  for (int s = 0; s < S; s++) { w[s] = __expf(w[s] - mx); sum += w[s]; }
  const float inv = 1.f / sum;

  float o[16];
#pragma unroll
  for (int e = 0; e < 16; e++) o[e] = 0.f;
#pragma unroll
  for (int s = 0; s < S; s++) {
    if (s < L) {
      const float ws = w[s];
      const float* vr = &VL[h][s][j * 16];
#pragma unroll
      for (int e = 0; e < 4; e++) {
        const float4 vv = *(const float4*)(vr + e * 4);
        o[e * 4 + 0] = fmaf(ws, vv.x, o[e * 4 + 0]);
        o[e * 4 + 1] = fmaf(ws, vv.y, o[e * 4 + 1]);
        o[e * 4 + 2] = fmaf(ws, vv.z, o[e * 4 + 2]);
        o[e * 4 + 3] = fmaf(ws, vv.w, o[e * 4 + 3]);
      }
    }
  }
  uint4 st0, st1;
  st0.x = pack2(o[0] * inv, o[1] * inv);   st0.y = pack2(o[2] * inv, o[3] * inv);
  st0.z = pack2(o[4] * inv, o[5] * inv);   st0.w = pack2(o[6] * inv, o[7] * inv);
  st1.x = pack2(o[8] * inv, o[9] * inv);   st1.y = pack2(o[10] * inv, o[11] * inv);
  st1.z = pack2(o[12] * inv, o[13] * inv); st1.w = pack2(o[14] * inv, o[15] * inv);
  ushort* op = O + (i64)(base + q) * 256 + h * 64 + j * 16;
  *(uint4*)op = st0;
  *(uint4*)(op + 8) = st1;
}

// ===== Layer-2 attention, CLS query. Q compact [nSeq,256], KV compact [Mv,512]
template <int S>
__global__ __launch_bounds__(256) void attn_cls_k(const ushort* __restrict__ Qc,
                                                  const ushort* __restrict__ KV,
                                                  const int* __restrict__ ss,
                                                  ushort* __restrict__ Ocls) {
  const int tid = threadIdx.x;
  const int sl = tid >> 4, h = (tid >> 2) & 3, j = tid & 3;
  const int seq = blockIdx.x * 16 + sl;
  const int base = ss[seq] - ss[0];
  const int L = ss[seq + 1] - ss[seq];

  float qv[16];
  {
    const ushort* qp = Qc + (i64)seq * 256 + h * 64 + j * 16;
    cvt8(*(const uint4*)qp, qv);
    cvt8(*(const uint4*)(qp + 8), qv + 8);
  }
  float w[S];
  float mx = -1e30f;
#pragma unroll
  for (int s = 0; s < S; s++) {
    float p = -1e30f;
    if (s < L) {
      float kf[16];
      const ushort* kp = KV + (i64)(base + s) * 512 + h * 64 + j * 16;
      cvt8(*(const uint4*)kp, kf);
      cvt8(*(const uint4*)(kp + 8), kf + 8);
      p = 0.f;
#pragma unroll
      for (int e = 0; e < 16; e++) p = fmaf(qv[e], kf[e], p);
      p += __shfl_xor(p, 1, 64);
      p += __shfl_xor(p, 2, 64);
      p *= 0.125f;
    }
    w[s] = p;
    mx = fmaxf(mx, p);
  }
  float sum = 0.f;
#pragma unroll
  for (int s = 0; s < S; s++) { w[s] = __expf(w[s] - mx); sum += w[s]; }
  const float inv = 1.f / sum;

  float o[16];
#pragma unroll
  for (int e = 0; e < 16; e++) o[e] = 0.f;
#pragma unroll
  for (int s = 0; s < S; s++) {
    if (s < L) {
      float vf[16];
      const ushort* vp = KV + (i64)(base + s) * 512 + 256 + h * 64 + j * 16;
      cvt8(*(const uint4*)vp, vf);
      cvt8(*(const uint4*)(vp + 8), vf + 8);
      const float ws = w[s];
#pragma unroll
      for (int e = 0; e < 16; e++) o[e] = fmaf(ws, vf[e], o[e]);
    }
  }
  uint4 st0, st1;
  st0.x = pack2(o[0] * inv, o[1] * inv);   st0.y = pack2(o[2] * inv, o[3] * inv);
  st0.z = pack2(o[4] * inv, o[5] * inv);   st0.w = pack2(o[6] * inv, o[7] * inv);
  st1.x = pack2(o[8] * inv, o[9] * inv);   st1.y = pack2(o[10] * inv, o[11] * inv);
  st1.z = pack2(o[12] * inv, o[13] * inv); st1.w = pack2(o[14] * inv, o[15] * inv);
  ushort* op = Ocls + (i64)seq * 256 + h * 64 + j * 16;
  *(uint4*)op = st0;
  *(uint4*)(op + 8) = st1;
}

// ================= gathers / scatters / conversion =============================
__global__ __launch_bounds__(256) void f2b_cvt_k(const float* __restrict__ in,
                                                 ushort* __restrict__ out, int n) {
  for (int i = blockIdx.x * 256 + threadIdx.x; i < n; i += gridDim.x * 256)
    out[i] = f2b(in[i]);
}

__global__ __launch_bounds__(256) void gather_v2e_k(const float* __restrict__ unity,
                                                    const float* __restrict__ pos,
                                                    const int* __restrict__ xid,
                                                    const int* __restrict__ xpos,
                                                    const int* __restrict__ tok,
                                                    const int* __restrict__ ss, int nseq,
                                                    ushort* __restrict__ X) {
  const int t = blockIdx.x * 4 + (threadIdx.x >> 6);
  const int lane = threadIdx.x & 63;
  const int s0 = ss[0];
  if (t >= ss[nseq] - s0) return;
  const int code = tok[s0 + t];
  const int e = code >> 5, slot = code & 31;
  float4 v = make_float4(0.f, 0.f, 0.f, 0.f);
  if (slot > 0) {
    const int id = xid[(i64)e * ARITY + (slot - 1)];
    v = *(const float4*)&unity[(i64)id * 256 + lane * 4];
  }
  const int pp = xpos[(i64)e * SV + slot];
  const float4 pv = *(const float4*)&pos[(i64)pp * 256 + lane * 4];
  uint2 o;
  o.x = pack2(v.x + pv.x, v.y + pv.y);
  o.y = pack2(v.z + pv.z, v.w + pv.w);
  *(uint2*)&X[(i64)t * 256 + lane * 4] = o;
}

__global__ __launch_bounds__(256) void gather_e2v_k(const ushort* __restrict__ ext,
                                                    const int* __restrict__ hid,
                                                    const int* __restrict__ tok,
                                                    const int* __restrict__ ss, int nseq,
                                                    ushort* __restrict__ X) {
  const int t = blockIdx.x * 4 + (threadIdx.x >> 6);
  const int lane = threadIdx.x & 63;
  const int s0 = ss[0];
  if (t >= ss[nseq] - s0) return;
  const int code = tok[s0 + t];
  const int n = code >> 5, slot = code & 31;
  const int id = hid[(i64)n * SE + slot];
  *(uint2*)&X[(i64)t * 256 + lane * 4] =
      *(const uint2*)&ext[(i64)id * 256 + lane * 4];
}

__global__ __launch_bounds__(256) void scatter_k(const ushort* __restrict__ Xc,
                                                 const int* __restrict__ subg,
                                                 float* __restrict__ unity, int n0) {
  const int nl = blockIdx.x * 4 + (threadIdx.x >> 6);
  const int lane = threadIdx.x & 63;
  const int dst = subg[n0 + nl];
  ushort4 v = *(const ushort4*)&Xc[(i64)nl * 256 + lane * 4];
  float4 o; o.x = b2f(v.x); o.y = b2f(v.y); o.z = b2f(v.z); o.w = b2f(v.w);
  *(float4*)&unity[(i64)dst * 256 + lane * 4] = o;
}

__global__ __launch_bounds__(256) void ext_init_k(ushort* __restrict__ ext,
                                                  const float* __restrict__ pad,
                                                  const float* __restrict__ cls) {
  const int d = threadIdx.x;
  ext[(i64)NHEDGE * 256 + d] = f2b(pad[d]);
  ext[(i64)(NHEDGE + 1) * 256 + d] = f2b(cls[d]);
}

__global__ __launch_bounds__(256) void out_gather_k(const ushort* __restrict__ ext,
                                                    const int* __restrict__ pred,
                                                    float* __restrict__ out) {
  const int i = blockIdx.x * 4 + (threadIdx.x >> 6);
  const int lane = threadIdx.x & 63;
  const int e = pred[i];
  ushort4 v = *(const ushort4*)&ext[(i64)e * 256 + lane * 4];
  float4 o; o.x = b2f(v.x); o.y = b2f(v.y); o.z = b2f(v.z); o.w = b2f(v.w);
  *(float4*)&out[(i64)i * 256 + lane * 4] = o;
}

// ================= host orchestration ==========================================
extern "C" void kernel_launch(void* const* d_in, const int* in_sizes, int n_in,
                              void* d_out, int out_size, void* d_ws, size_t ws_size,
                              hipStream_t stream) {
  (void)in_sizes; (void)n_in; (void)out_size;
  const float* unity_in = (const float*)d_in[0];
  const float* cls_emb  = (const float*)d_in[1];
  const float* pad_emb  = (const float*)d_in[2];
  const float* pos_tab  = (const float*)d_in[3];
  const float* qkv_w    = (const float*)d_in[4];
  const float* qkv_b    = (const float*)d_in[5];
  const float* out_w    = (const float*)d_in[6];
  const float* out_b    = (const float*)d_in[7];
  const float* ln1_g    = (const float*)d_in[8];
  const float* ln1_b    = (const float*)d_in[9];
  const float* ln2_g    = (const float*)d_in[10];
  const float* ln2_b    = (const float*)d_in[11];
  const float* ff1_w    = (const float*)d_in[12];
  const float* ff1_b    = (const float*)d_in[13];
  const float* ff2_w    = (const float*)d_in[14];
  const float* ff2_b    = (const float*)d_in[15];
  const int* xid   = (const int*)d_in[16];
  const int* vmask = (const int*)d_in[17];
  const int* xpos  = (const int*)d_in[18];
  const int* hid   = (const int*)d_in[19];
  const int* hmask = (const int*)d_in[20];
  const int* subg  = (const int*)d_in[21];
  const int* pred  = (const int*)d_in[22];

  const i64 unity_b = (i64)NTOTAL * 256 * 4;
  const i64 ext_b   = (i64)(NHEDGE + 2) * 256 * 2;
  const int nq = 2 * 768 * 256, no = 2 * 256 * 256,
            n1 = 2 * 1024 * 256, n2 = 2 * 256 * 1024;
  const i64 wts_b = (i64)(nq + no + n1 + n2) * 2;
  const i64 idx_b = ((i64)NNODE + NHEDGE + 512 +
                     (NNODE + 1) + (NHEDGE + 1) +
                     (i64)NNODE * SE + (i64)NHEDGE * SV) * 4;
  const i64 per_elem = (i64)SE * (512 + 2048 + 512);  // X+Y+O worst-case bytes
  int CHUNK = 8192;
  while (CHUNK > 128 &&
         unity_b + ext_b + wts_b + idx_b + (i64)CHUNK * per_elem > (i64)ws_size)
    CHUNK >>= 1;

  char* w = (char*)d_ws;
  float*  unity = (float*)w;  w += unity_b;
  ushort* ext   = (ushort*)w; w += ext_b;
  ushort* wq    = (ushort*)w; w += (i64)nq * 2;
  ushort* wo    = (ushort*)w; w += (i64)no * 2;
  ushort* w1    = (ushort*)w; w += (i64)n1 * 2;
  ushort* w2    = (ushort*)w; w += (i64)n2 * 2;
  ushort* X     = (ushort*)w; w += (i64)CHUNK * SE * 256 * 2;
  ushort* Y     = (ushort*)w; w += (i64)CHUNK * SE * 1024 * 2;
  ushort* O     = (ushort*)w; w += (i64)CHUNK * SE * 256 * 2;
  int* cntE  = (int*)w; w += (i64)NNODE * 4;
  int* cntV  = (int*)w; w += (i64)NHEDGE * 4;
  int* partE = (int*)w; w += 256 * 4;
  int* partV = (int*)w; w += 256 * 4;
  int* ssE   = (int*)w; w += (i64)(NNODE + 1) * 4;
  int* ssV   = (int*)w; w += (i64)(NHEDGE + 1) * 4;
  int* tokE  = (int*)w; w += (i64)NNODE * SE * 4;
  int* tokV  = (int*)w; w += (i64)NHEDGE * SV * 4;
  // layer-1 compact buffers carved from O (dead after l0 proj)
  ushort* Ocls = O;
  ushort* Qcls = O + (i64)CHUNK * 256;
  ushort* X2   = O + (i64)2 * CHUNK * 256;
  ushort* X3   = O + (i64)3 * CHUNK * 256;

  f2b_cvt_k<<<512, 256, 0, stream>>>(qkv_w, wq, nq);
  f2b_cvt_k<<<512, 256, 0, stream>>>(out_w, wo, no);
  f2b_cvt_k<<<512, 256, 0, stream>>>(ff1_w, w1, n1);
  f2b_cvt_k<<<512, 256, 0, stream>>>(ff2_w, w2, n2);
  hipMemcpyAsync(unity, unity_in, unity_b, hipMemcpyDeviceToDevice, stream);
  ext_init_k<<<1, 256, 0, stream>>>(ext, pad_emb, cls_emb);

  // compaction index build (masks are static): V2E over hedges, E2V over nodes
  cnt_k<<<NHEDGE / 256, 256, 0, stream>>>(vmask, ARITY, 1, cntV, NHEDGE);
  scan1_k<<<NHEDGE / 256, 256, 0, stream>>>(cntV, ssV, partV, NHEDGE);
  scan2_k<<<1, 256, 0, stream>>>(partV, NHEDGE / 256, ssV, NHEDGE);
  scan3_k<<<NHEDGE / 256, 256, 0, stream>>>(ssV, partV, vmask, ARITY, 1, tokV, NHEDGE);
  cnt_k<<<NNODE / 256, 256, 0, stream>>>(hmask, SE, 0, cntE, NNODE);
  scan1_k<<<NNODE / 256, 256, 0, stream>>>(cntE, ssE, partE, NNODE);
  scan2_k<<<1, 256, 0, stream>>>(partE, NNODE / 256, ssE, NNODE);
  scan3_k<<<NNODE / 256, 256, 0, stream>>>(ssE, partE, hmask, SE, 0, tokE, NNODE);

  for (int k = 0; k <= 2; k++) {
    // ---- V2E ----
    for (int c = 0; c < NHEDGE / CHUNK; c++) {
      const int e0 = c * CHUNK;
      const int* ssc = ssV + e0;
      const int Mmax = CHUNK * SV;
      gather_v2e_k<<<Mmax / 4, 256, 0, stream>>>(unity, pos_tab, xid, xpos,
                                                 tokV, ssc, CHUNK, X);
      // layer 0 (full, compact)
      gemm_bf16_k<256, 1><<<dim3(6, Mmax / 128), 256, 0, stream>>>(
          X, wq, qkv_b, Y, Mmax, 768, ssc, CHUNK, nullptr);
      attn1_k<SV><<<CHUNK, 16 * SV, 0, stream>>>(Y, ssc, O);
      gemm_ln_k<256><<<Mmax / 128, 512, 0, stream>>>(
          O, wo, out_b, X, 256, ln1_g, ln1_b, X, 256, Mmax, ssc, CHUNK, nullptr);
      gemm_bf16_k<256, 2><<<dim3(8, Mmax / 128), 256, 0, stream>>>(
          X, w1, ff1_b, Y, Mmax, 1024, ssc, CHUNK, nullptr);
      gemm_ln_k<1024><<<Mmax / 128, 512, 0, stream>>>(
          Y, w2, ff2_b, X, 256, ln2_g, ln2_b, X, 256, Mmax, ssc, CHUNK, nullptr);
      // layer 1: KV for all compact tokens, Q for CLS only
      gemm_bf16_k<256, 1><<<dim3(4, Mmax / 128), 256, 0, stream>>>(
          X, wq + (i64)768 * 256 + (i64)256 * 256, qkv_b + 768 + 256,
          Y, Mmax, 512, ssc, CHUNK, nullptr);
      gemm_bf16_k<256, 1><<<dim3(2, CHUNK / 128), 256, 0, stream>>>(
          X, wq + (i64)768 * 256, qkv_b + 768, Qcls, CHUNK, 256,
          nullptr, 0, ssc);
      attn_cls_k<SV><<<CHUNK / 16, 256, 0, stream>>>(Qcls, Y, ssc, Ocls);
      gemm_ln_k<256><<<CHUNK / 128, 512, 0, stream>>>(
          Ocls, wo + (i64)256 * 256, out_b + 256, X, 256,
          ln1_g + 256, ln1_b + 256, X2, 256, CHUNK, nullptr, 0, ssc);
      gemm_bf16_k<256, 2><<<dim3(8, CHUNK / 128), 256, 0, stream>>>(
          X2, w1 + (i64)1024 * 256, ff1_b + 1024, Y, CHUNK, 1024,
          nullptr, 0, nullptr);
      gemm_ln_k<1024><<<CHUNK / 128, 512, 0, stream>>>(
          Y, w2 + (i64)256 * 1024, ff2_b + 256, X2, 256,
          ln2_g + 256, ln2_b + 256, ext + (i64)e0 * 256, 256, CHUNK,
          nullptr, 0, nullptr);
    }
    // ---- E2V ----
    if (k < 2) {
      for (int c = 0; c < NNODE / CHUNK; c++) {
        const int n0 = c * CHUNK;
        const int* ssc = ssE + n0;
        const int Mmax = CHUNK * SE;
        gather_e2v_k<<<Mmax / 4, 256, 0, stream>>>(ext, hid, tokE, ssc, CHUNK, X);
        gemm_bf16_k<256, 1><<<dim3(6, Mmax / 128), 256, 0, stream>>>(
            X, wq, qkv_b, Y, Mmax, 768, ssc, CHUNK, nullptr);
        attn1_k<SE><<<CHUNK, 16 * SE, 0, stream>>>(Y, ssc, O);
        gemm_ln_k<256><<<Mmax / 128, 512, 0, stream>>>(
            O, wo, out_b, X, 256, ln1_g, ln1_b, X, 256, Mmax, ssc, CHUNK, nullptr);
        gemm_bf16_k<256, 2><<<dim3(8, Mmax / 128), 256, 0, stream>>>(
            X, w1, ff1_b, Y, Mmax, 1024, ssc, CHUNK, nullptr);
        gemm_ln_k<1024><<<Mmax / 128, 512, 0, stream>>>(
            Y, w2, ff2_b, X, 256, ln2_g, ln2_b, X, 256, Mmax, ssc, CHUNK, nullptr);
        gemm_bf16_k<256, 1><<<dim3(4, Mmax / 128), 256, 0, stream>>>(
            X, wq + (i64)768 * 256 + (i64)256 * 256, qkv_b + 768 + 256,
            Y, Mmax, 512, ssc, CHUNK, nullptr);
        gemm_bf16_k<256, 1><<<dim3(2, CHUNK / 128), 256, 0, stream>>>(
            X, wq + (i64)768 * 256, qkv_b + 768, Qcls, CHUNK, 256,
            nullptr, 0, ssc);
        attn_cls_k<SE><<<CHUNK / 16, 256, 0, stream>>>(Qcls, Y, ssc, Ocls);
        gemm_ln_k<256><<<CHUNK / 128, 512, 0, stream>>>(
            Ocls, wo + (i64)256 * 256, out_b + 256, X, 256,
            ln1_g + 256, ln1_b + 256, X2, 256, CHUNK, nullptr, 0, ssc);
        gemm_bf16_k<256, 2><<<dim3(8, CHUNK / 128), 256, 0, stream>>>(
            X2, w1 + (i64)1024 * 256, ff1_b + 1024, Y, CHUNK, 1024,
            nullptr, 0, nullptr);
        gemm_ln_k<1024><<<CHUNK / 128, 512, 0, stream>>>(
            Y, w2 + (i64)256 * 1024, ff2_b + 256, X2, 256,
            ln2_g + 256, ln2_b + 256, X3, 256, CHUNK, nullptr, 0, nullptr);
        scatter_k<<<CHUNK / 4, 256, 0, stream>>>(X3, subg, unity, n0);
      }
    }
  }
  out_gather_k<<<64, 256, 0, stream>>>(ext, pred, (float*)d_out);
}